// Round 8
// baseline (5603.234 us; speedup 1.0000x reference)
//
#include <hip/hip_runtime.h>
#include <hip/hip_bf16.h>
#include <hip/hip_cooperative_groups.h>
#include <math.h>

// EndoMamba r21: conv+xproj+scanA/B/C fused into ONE cooperative kernel
// (grid 768, grid.sync between phases, all phases grid-strided; per-item math
// verbatim from r20b -> bit-identical). Launches/layer 8 -> 4 (101 -> 53
// dispatches). Host-side fallback to the 5 legacy kernels if cooperative
// launch errors. Everything else from r20b kept (split-K x2 out_proj/patch,
// bf16 pre-cast weights, BK=64 dbuf GEMM, bijective XCD swizzle).
#define Bn   2
#define Tn   4
#define Nn   196
#define Ln   784
#define Mn   1568
#define En   384
#define Din  768
#define Sn   8
#define Rn   24
#define DEPTH 12
#define NSPA 6
#define NC   98
#define CL   8      // 784 = 98*8

typedef __attribute__((ext_vector_type(8))) short bf16x8;
typedef __attribute__((ext_vector_type(4))) float f32x4;

__device__ __forceinline__ float siluf(float v) { return v / (1.f + __expf(-v)); }
__device__ __forceinline__ float us2f(unsigned short u) {
    union { unsigned int i; float f; } v; v.i = (unsigned)u << 16; return v.f;
}
__device__ __forceinline__ unsigned short f2us(float f) {
    __hip_bfloat16 b = __float2bfloat16(f);
    return *(unsigned short*)&b;
}
__device__ __forceinline__ void cstore(float* p, float v) { *p = v; }
__device__ __forceinline__ void cstore(unsigned short* p, float v) { *p = f2us(v); }

// bijective XCD swizzle (m204): consecutive flats within an XCD share n-tile
__device__ __forceinline__ void xcd_tile(int ny, int& n0, int& m0)
{
    int nx = gridDim.x;
    int total = nx*ny;
    int bid = blockIdx.y*nx + blockIdx.x;
    int q = total >> 3, r = total & 7;
    int xcd = bid & 7, idx = bid >> 3;
    int base = (xcd < r) ? xcd*(q+1) : r*(q+1) + (xcd - r)*q;
    int flat = base + idx;
    n0 = (flat / ny) * 64;
    m0 = (flat % ny) * 64;
}

// -------------------- weight pre-cast fp32 -> bf16 (once per launch)
#define NW0 7077888   // in_proj 12*1536*384
#define NW1 3538944   // outproj 12*384*768
#define NW2 368640    // xproj fwd 12*40*768
#define NW3 184320    // xproj bwd 6*40*768
#define NW4 294912    // patch 384*768
__device__ __forceinline__ void cast4(unsigned short* d, const float* s)
{
    float4 v = *(const float4*)s;
    ushort4 o;
    o.x = f2us(v.x); o.y = f2us(v.y); o.z = f2us(v.z); o.w = f2us(v.w);
    *(ushort4*)d = o;
}
__global__ __launch_bounds__(256) void k_castw(
    const float* __restrict__ w0, const float* __restrict__ w1,
    const float* __restrict__ w2, const float* __restrict__ w3,
    const float* __restrict__ w4,
    unsigned short* __restrict__ o0, unsigned short* __restrict__ o1,
    unsigned short* __restrict__ o2, unsigned short* __restrict__ o3,
    unsigned short* __restrict__ o4)
{
    int i4 = (blockIdx.x*blockDim.x + threadIdx.x)*4;
    if (i4 < NW0) { cast4(o0+i4, w0+i4); return; }
    i4 -= NW0;
    if (i4 < NW1) { cast4(o1+i4, w1+i4); return; }
    i4 -= NW1;
    if (i4 < NW2) { cast4(o2+i4, w2+i4); return; }
    i4 -= NW2;
    if (i4 < NW3) { cast4(o3+i4, w3+i4); return; }
    i4 -= NW3;
    if (i4 < NW4) { cast4(o4+i4, w4+i4); }
}

// ------------------------------------------- patch gather -> pm[m,768] bf16
__global__ __launch_bounds__(256) void k_patch(
    const float* __restrict__ x, unsigned short* __restrict__ pm)
{
    int gid = blockIdx.x*blockDim.x + threadIdx.x;
    if (gid >= Mn*768) return;
    int idx = gid % 768, token = gid / 768;
    int b = token / Ln, l = token % Ln;
    int t = l / Nn, n = l % Nn;
    int hh = n / 14, ww = n % 14;
    int c = idx >> 8, rem = idx & 255, p = rem >> 4, q = rem & 15;
    pm[gid] = f2us(x[(((size_t)(b*3 + c)*Tn + t)*224 + (hh*16 + p))*224 + (ww*16 + q)]);
}

// ---------------- embed epilogue: h = h + h2 + pb + pos + pe (split-K add)
__global__ __launch_bounds__(256) void k_posadd(
    float* __restrict__ h, const float* __restrict__ h2,
    const float* __restrict__ pb, const float* __restrict__ pos)
{
    int gid = blockIdx.x*blockDim.x + threadIdx.x;
    if (gid >= Mn*En) return;
    int e = gid % En, token = gid / En;
    int l = token % Ln;
    int t = l / Nn, n = l % Nn;
    float div = __expf(-logf(10000.f) * (float)(e & ~1) / (float)En);
    float ang = (float)t * div;
    h[gid] += h2[gid] + pb[e] + pos[n*En + e] + ((e & 1) ? cosf(ang) : sinf(ang));
}

// -------------------- rmsnorm (+ residual); h2 = split-K partial of out_proj
__global__ __launch_bounds__(256) void rms_residual(
    const float* __restrict__ hin, const float* __restrict__ h2,
    float* __restrict__ res, unsigned short* __restrict__ hn,
    const float* __restrict__ w, int first)
{
    int wid  = (blockIdx.x * blockDim.x + threadIdx.x) >> 6;   // token
    int lane = threadIdx.x & 63;
    if (wid >= Mn) return;
    const float* hp = hin + (size_t)wid*En;
    const float* h2p = h2 + (size_t)wid*En;
    float* rp = res + (size_t)wid*En;
    float v[6]; float ss = 0.f;
    #pragma unroll
    for (int j = 0; j < 6; ++j) {
        int e = lane + j*64;
        float r = first ? hp[e] : (hp[e] + h2p[e] + rp[e]);
        v[j] = r; ss = fmaf(r, r, ss);
    }
    #pragma unroll
    for (int off = 32; off; off >>= 1) ss += __shfl_xor(ss, off, 64);
    float scale = rsqrtf(ss * (1.f/(float)En) + 1e-5f);
    #pragma unroll
    for (int j = 0; j < 6; ++j) {
        int e = lane + j*64;
        rp[e] = v[j];
        hn[(size_t)wid*En + e] = f2us(v[j] * scale * w[e]);
    }
}

// ---------------- bf16 MFMA GEMM: C = A[M,K] * Wb[N,K]^T, Wb bf16 (pre-cast)
// BK=64 double-buffered, one barrier per step, XCD-swizzled tiles.
// SK: split-K factor; z-th partial written to C + z*M*ldc.
// GATED: A_eff = (yf + (ndir==2? yb:0)) * silu(z), all bf16 inputs.
template<typename CT, int GATED, int SK>
__global__ __launch_bounds__(256) void gemm_mfma(
    const unsigned short* __restrict__ A,     // bf16 A (or yf when GATED)
    const unsigned short* __restrict__ Yb,    // yb (GATED only)
    const unsigned short* __restrict__ Z,     // z base, row stride 1536 (GATED)
    const unsigned short* __restrict__ Wb,    // bf16 W [N][K]
    CT* __restrict__ C, int ldc, int M, int N, int K, int ndir)
{
    __shared__ unsigned short As[2][64][72];   // 64 k + 8 pad
    __shared__ unsigned short Bs[2][64][72];
    int n0, m0;
    xcd_tile((M + 63) >> 6, n0, m0);
    int nidx = n0 >> 6;
    int zk = nidx % SK;
    n0 = (nidx / SK) * 64;
    int kbeg = zk * (K / SK);
    int kend = kbeg + K / SK;
    CT* Cz = C + (size_t)zk*M*ldc;
    int tid = threadIdx.x;
    int wave = tid >> 6, lane = tid & 63;
    int quad = lane >> 4, fr = lane & 15;
    int arow = tid >> 2;            // 0..63
    int c8   = (tid & 3) << 3;      // 0,8,16,24
    int mg = m0 + arow; if (mg >= M) mg = M - 1;
    f32x4 acc[4] = {};

    auto gate8 = [&](const unsigned short* yf, const unsigned short* yb,
                     const unsigned short* zp) -> bf16x8 {
        bf16x8 f = *(const bf16x8*)yf;
        bf16x8 bb = *(const bf16x8*)yb;
        bf16x8 zz = *(const bf16x8*)zp;
        unsigned short o[8];
        const unsigned short* fu = (const unsigned short*)&f;
        const unsigned short* bu = (const unsigned short*)&bb;
        const unsigned short* zu = (const unsigned short*)&zz;
        #pragma unroll
        for (int j = 0; j < 8; ++j) {
            float v = us2f(fu[j]);
            if (ndir == 2) v += us2f(bu[j]);
            o[j] = f2us(v * siluf(us2f(zu[j])));
        }
        return *(bf16x8*)o;
    };

    auto load_tile = [&](int k0, bf16x8& av0, bf16x8& av1,
                         bf16x8& wv0, bf16x8& wv1) {
        if (!GATED) {
            av0 = *(const bf16x8*)(A + (size_t)mg*K + k0 + c8);
            av1 = *(const bf16x8*)(A + (size_t)mg*K + k0 + c8 + 32);
        } else {
            size_t ro = (size_t)mg*K + k0 + c8;
            size_t zo = (size_t)mg*1536 + k0 + c8;
            av0 = gate8(A + ro, Yb + ro, Z + zo);
            av1 = gate8(A + ro + 32, Yb + ro + 32, Z + zo + 32);
        }
        wv0 = *(const bf16x8*)(Wb + (size_t)(n0 + arow)*K + k0 + c8);
        wv1 = *(const bf16x8*)(Wb + (size_t)(n0 + arow)*K + k0 + c8 + 32);
    };

    {   // prologue: stage first k-tile into buffer 0
        bf16x8 a0, a1, w0, w1;
        load_tile(kbeg, a0, a1, w0, w1);
        *(bf16x8*)&As[0][arow][c8]      = a0;
        *(bf16x8*)&As[0][arow][c8 + 32] = a1;
        *(bf16x8*)&Bs[0][arow][c8]      = w0;
        *(bf16x8*)&Bs[0][arow][c8 + 32] = w1;
    }
    int cur = 0;
    for (int k0 = kbeg + 64; k0 <= kend; k0 += 64) {
        bool more = (k0 < kend);
        bf16x8 a0, a1, w0, w1;
        if (more) load_tile(k0, a0, a1, w0, w1);   // issue loads before barrier
        __syncthreads();
        bf16x8 af0 = *(const bf16x8*)&As[cur][wave*16 + fr][quad << 3];
        bf16x8 af1 = *(const bf16x8*)&As[cur][wave*16 + fr][(quad << 3) + 32];
        #pragma unroll
        for (int nt = 0; nt < 4; ++nt) {
            bf16x8 b0 = *(const bf16x8*)&Bs[cur][nt*16 + fr][quad << 3];
            bf16x8 b1 = *(const bf16x8*)&Bs[cur][nt*16 + fr][(quad << 3) + 32];
            acc[nt] = __builtin_amdgcn_mfma_f32_16x16x32_bf16(af0, b0, acc[nt], 0, 0, 0);
            acc[nt] = __builtin_amdgcn_mfma_f32_16x16x32_bf16(af1, b1, acc[nt], 0, 0, 0);
        }
        if (more) {
            *(bf16x8*)&As[cur^1][arow][c8]      = a0;
            *(bf16x8*)&As[cur^1][arow][c8 + 32] = a1;
            *(bf16x8*)&Bs[cur^1][arow][c8]      = w0;
            *(bf16x8*)&Bs[cur^1][arow][c8 + 32] = w1;
            cur ^= 1;
        }
    }
    #pragma unroll
    for (int nt = 0; nt < 4; ++nt) {
        #pragma unroll
        for (int r = 0; r < 4; ++r) {
            int mgo = m0 + wave*16 + quad*4 + r;
            if (mgo < M) cstore(Cz + (size_t)mgo*ldc + n0 + nt*16 + fr, acc[nt][r]);
        }
    }
}

// ---------------------- parameters for the fused cooperative SSM-middle
struct CoopP {
    const unsigned short* xz;
    const float *cwf, *cbf, *cwb, *cbb;
    const unsigned short *xwf, *xwb;
    unsigned short* u;
    float* xd;
    const float *dwf, *dbf, *dwb, *dbb, *Alf, *Alb, *Dpf, *Dpb;
    float *Hsum, *dtsum;
    unsigned short* yt;
    int ndir;
};

// One cooperative launch per layer: conv -> xproj(MFMA) -> scanA -> scanB ->
// scanC with grid.sync between phases. Per-item math identical to the legacy
// kernels (bit-identical results); only the thread->item mapping grid-strides.
__global__ __launch_bounds__(256, 4) void coop_scan(CoopP p)
{
    namespace cg = cooperative_groups;
    cg::grid_group grid = cg::this_grid();
    __shared__ unsigned short As[2][64][72];
    __shared__ unsigned short Bs[2][64][72];
    int tid = threadIdx.x;
    int gid0 = blockIdx.x*blockDim.x + tid;
    int gstride = gridDim.x*blockDim.x;

    // ---------------- P0: u = silu(conv(xz))
    for (int gid = gid0; gid < p.ndir*Mn*Din; gid += gstride) {
        int dir = gid / (Mn*Din);
        int rem = gid % (Mn*Din);
        int d = rem % Din, m = rem / Din;
        int l = m % Ln, b = m / Ln;
        const float* cw = dir ? p.cwb : p.cwf;
        const float* cb = dir ? p.cbb : p.cbf;
        float4 cwv = *(const float4*)(cw + d*4);
        float acc = cb[d];
        #pragma unroll
        for (int k = 0; k < 4; ++k) {
            int ls = l - 3 + k;
            if (ls < 0) continue;
            int lsrc = dir ? (Ln - 1 - ls) : ls;
            float cwk = (k==0)?cwv.x:(k==1)?cwv.y:(k==2)?cwv.z:cwv.w;
            acc = fmaf(us2f(p.xz[(size_t)(b*Ln + lsrc)*1536 + d]), cwk, acc);
        }
        p.u[gid] = f2us(siluf(acc));
    }
    grid.sync();

    // ---------------- P1: xd = u * xw^T (MFMA, 64-wide N-tile)
    for (int tile = blockIdx.x; tile < p.ndir*25; tile += gridDim.x) {
        int dir = tile / 25;
        int m0 = (tile % 25) * 64;
        const unsigned short* A = p.u + (size_t)dir*Mn*Din;
        const unsigned short* W = dir ? p.xwb : p.xwf;
        float* C = p.xd + (size_t)dir*Mn*40;
        int wave = tid >> 6, lane = tid & 63;
        int quad = lane >> 4, fr = lane & 15;
        int arow = tid >> 2;
        int c8   = (tid & 3) << 3;
        int mg = m0 + arow; if (mg >= Mn) mg = Mn - 1;
        int wrow = arow < 40 ? arow : 39;
        f32x4 acc[4] = {};
        {
            bf16x8 a0 = *(const bf16x8*)(A + (size_t)mg*Din + c8);
            bf16x8 a1 = *(const bf16x8*)(A + (size_t)mg*Din + c8 + 32);
            bf16x8 w0 = *(const bf16x8*)(W + (size_t)wrow*Din + c8);
            bf16x8 w1 = *(const bf16x8*)(W + (size_t)wrow*Din + c8 + 32);
            *(bf16x8*)&As[0][arow][c8]      = a0;
            *(bf16x8*)&As[0][arow][c8 + 32] = a1;
            *(bf16x8*)&Bs[0][arow][c8]      = w0;
            *(bf16x8*)&Bs[0][arow][c8 + 32] = w1;
        }
        int cur = 0;
        for (int k0 = 64; k0 <= Din; k0 += 64) {
            bool more = (k0 < Din);
            bf16x8 a0, a1, w0, w1;
            if (more) {
                a0 = *(const bf16x8*)(A + (size_t)mg*Din + k0 + c8);
                a1 = *(const bf16x8*)(A + (size_t)mg*Din + k0 + c8 + 32);
                w0 = *(const bf16x8*)(W + (size_t)wrow*Din + k0 + c8);
                w1 = *(const bf16x8*)(W + (size_t)wrow*Din + k0 + c8 + 32);
            }
            __syncthreads();
            bf16x8 af0 = *(const bf16x8*)&As[cur][wave*16 + fr][quad << 3];
            bf16x8 af1 = *(const bf16x8*)&As[cur][wave*16 + fr][(quad << 3) + 32];
            #pragma unroll
            for (int nt = 0; nt < 4; ++nt) {
                bf16x8 b0 = *(const bf16x8*)&Bs[cur][nt*16 + fr][quad << 3];
                bf16x8 b1 = *(const bf16x8*)&Bs[cur][nt*16 + fr][(quad << 3) + 32];
                acc[nt] = __builtin_amdgcn_mfma_f32_16x16x32_bf16(af0, b0, acc[nt], 0, 0, 0);
                acc[nt] = __builtin_amdgcn_mfma_f32_16x16x32_bf16(af1, b1, acc[nt], 0, 0, 0);
            }
            if (more) {
                *(bf16x8*)&As[cur^1][arow][c8]      = a0;
                *(bf16x8*)&As[cur^1][arow][c8 + 32] = a1;
                *(bf16x8*)&Bs[cur^1][arow][c8]      = w0;
                *(bf16x8*)&Bs[cur^1][arow][c8 + 32] = w1;
                cur ^= 1;
            }
        }
        #pragma unroll
        for (int nt = 0; nt < 4; ++nt) {
            int col = nt*16 + fr;
            if (col >= 40) continue;
            #pragma unroll
            for (int r = 0; r < 4; ++r) {
                int mgo = m0 + wave*16 + quad*4 + r;
                if (mgo < Mn) C[(size_t)mgo*40 + col] = acc[nt][r];
            }
        }
        __syncthreads();   // LDS safe for potential next tile
    }
    grid.sync();

    // ---------------- P2: scanA (per-chunk Sdt, H[8])
    for (int gid = gid0; gid < p.ndir*Bn*NC*Din; gid += gstride) {
        int dir = gid / (Bn*NC*Din);
        int rem = gid % (Bn*NC*Din);
        int d = rem % Din;
        int bc = rem / Din;
        int c = bc % NC, b = bc / NC;
        const float* A_log = dir ? p.Alb : p.Alf;
        const float* dw = dir ? p.dwb : p.dwf;
        const float* db = dir ? p.dbb : p.dbf;
        float A[Sn];
        #pragma unroll
        for (int s = 0; s < Sn; ++s) A[s] = -__expf(A_log[d*Sn + s]);
        float dwr[Rn];
        #pragma unroll
        for (int r = 0; r < Rn; ++r) dwr[r] = dw[d*Rn + r];
        float dbv = db[d];
        float hs[Sn] = {0,0,0,0,0,0,0,0};
        float sdt = 0.f;
        int l0 = c*CL;
        const unsigned short* up = p.u + (size_t)dir*Mn*Din + ((size_t)b*Ln + l0)*Din + d;
        const float* xp = p.xd + (size_t)dir*Mn*40 + ((size_t)b*Ln + l0)*40;
        #pragma unroll
        for (int l = 0; l < CL; ++l) {
            float uv = us2f(up[(size_t)l*Din]);
            const float* xr = xp + l*40;
            float dta = dbv;
            #pragma unroll
            for (int r = 0; r < Rn; ++r) dta = fmaf(xr[r], dwr[r], dta);
            float dtv = (dta > 20.f) ? dta : log1pf(__expf(dta));
            sdt += dtv;
            const float4* B4 = (const float4*)(xr + Rn);
            float4 Bv0 = B4[0], Bv1 = B4[1];
            float du = dtv * uv;
            hs[0] = fmaf(__expf(dtv*A[0]), hs[0], du*Bv0.x);
            hs[1] = fmaf(__expf(dtv*A[1]), hs[1], du*Bv0.y);
            hs[2] = fmaf(__expf(dtv*A[2]), hs[2], du*Bv0.z);
            hs[3] = fmaf(__expf(dtv*A[3]), hs[3], du*Bv0.w);
            hs[4] = fmaf(__expf(dtv*A[4]), hs[4], du*Bv1.x);
            hs[5] = fmaf(__expf(dtv*A[5]), hs[5], du*Bv1.y);
            hs[6] = fmaf(__expf(dtv*A[6]), hs[6], du*Bv1.z);
            hs[7] = fmaf(__expf(dtv*A[7]), hs[7], du*Bv1.w);
        }
        float4* Hp = (float4*)(p.Hsum + (size_t)gid*8);
        Hp[0] = make_float4(hs[0], hs[1], hs[2], hs[3]);
        Hp[1] = make_float4(hs[4], hs[5], hs[6], hs[7]);
        p.dtsum[gid] = sdt;
    }
    grid.sync();

    // ---------------- P3: scanB serial fixup in-place on Hsum
    for (int gid = gid0; gid < p.ndir*Bn*Din*Sn; gid += gstride) {
        int s   = gid & 7;
        int rem = gid >> 3;
        int d   = rem % Din;
        int t   = rem / Din;
        int b   = t % Bn, dir = t / Bn;
        const float* A_log = dir ? p.Alb : p.Alf;
        float Av = -__expf(A_log[d*Sn + s]);
        float h = 0.f;
        size_t base = (size_t)dir*Bn*NC*Din + (size_t)b*NC*Din + d;
        float* Hp = p.Hsum + base*8 + s;
        const float* dp = p.dtsum + base;
        #pragma unroll 7
        for (int c = 0; c < NC; ++c) {
            size_t off = (size_t)c*Din;
            float H = Hp[off*8];
            float sdt = dp[off];
            Hp[off*8] = h;
            h = fmaf(__expf(Av*sdt), h, H);
        }
    }
    grid.sync();

    // ---------------- P4: scanC seeded local scan, raw y emit
    for (int gid = gid0; gid < p.ndir*Bn*NC*Din; gid += gstride) {
        int dir = gid / (Bn*NC*Din);
        int rem = gid % (Bn*NC*Din);
        int d = rem % Din;
        int bc = rem / Din;
        int c = bc % NC, b = bc / NC;
        const float* A_log = dir ? p.Alb : p.Alf;
        const float* dw = dir ? p.dwb : p.dwf;
        const float* db = dir ? p.dbb : p.dbf;
        const float* Dp = dir ? p.Dpb : p.Dpf;
        float A[Sn];
        #pragma unroll
        for (int s = 0; s < Sn; ++s) A[s] = -__expf(A_log[d*Sn + s]);
        float dwr[Rn];
        #pragma unroll
        for (int r = 0; r < Rn; ++r) dwr[r] = dw[d*Rn + r];
        float dbv = db[d];
        const float4* hp = (const float4*)(p.Hsum + (size_t)gid*8);
        float4 h0 = hp[0], h1 = hp[1];
        float hs[Sn] = {h0.x, h0.y, h0.z, h0.w, h1.x, h1.y, h1.z, h1.w};
        float Dd = Dp[d];
        int l0 = c*CL;
        const unsigned short* up = p.u + (size_t)dir*Mn*Din + ((size_t)b*Ln + l0)*Din + d;
        const float* xp = p.xd + (size_t)dir*Mn*40 + ((size_t)b*Ln + l0)*40;
        unsigned short* yp = p.yt + (size_t)dir*Mn*Din + (size_t)b*Ln*Din + d;
        #pragma unroll
        for (int l = 0; l < CL; ++l) {
            int gl = l0 + l;
            float uv = us2f(up[(size_t)l*Din]);
            const float* xr = xp + l*40;
            float dta = dbv;
            #pragma unroll
            for (int r = 0; r < Rn; ++r) dta = fmaf(xr[r], dwr[r], dta);
            float dtv = (dta > 20.f) ? dta : log1pf(__expf(dta));
            const float4* B4 = (const float4*)(xr + Rn);
            float4 Bv0 = B4[0], Bv1 = B4[1], Cv0 = B4[2], Cv1 = B4[3];
            float du = dtv * uv;
            float yv = 0.f;
            hs[0] = fmaf(__expf(dtv*A[0]), hs[0], du*Bv0.x); yv = fmaf(hs[0], Cv0.x, yv);
            hs[1] = fmaf(__expf(dtv*A[1]), hs[1], du*Bv0.y); yv = fmaf(hs[1], Cv0.y, yv);
            hs[2] = fmaf(__expf(dtv*A[2]), hs[2], du*Bv0.z); yv = fmaf(hs[2], Cv0.z, yv);
            hs[3] = fmaf(__expf(dtv*A[3]), hs[3], du*Bv0.w); yv = fmaf(hs[3], Cv0.w, yv);
            hs[4] = fmaf(__expf(dtv*A[4]), hs[4], du*Bv1.x); yv = fmaf(hs[4], Cv1.x, yv);
            hs[5] = fmaf(__expf(dtv*A[5]), hs[5], du*Bv1.y); yv = fmaf(hs[5], Cv1.y, yv);
            hs[6] = fmaf(__expf(dtv*A[6]), hs[6], du*Bv1.z); yv = fmaf(hs[6], Cv1.z, yv);
            hs[7] = fmaf(__expf(dtv*A[7]), hs[7], du*Bv1.w); yv = fmaf(hs[7], Cv1.w, yv);
            yv = fmaf(uv, Dd, yv);
            int ol = dir ? (Ln - 1 - gl) : gl;
            yp[(size_t)ol*Din] = f2us(yv);
        }
    }
}

// ---------------------------------- legacy fallback kernels (r20b verbatim)
__global__ __launch_bounds__(256) void k_conv2(
    const unsigned short* __restrict__ xz,
    const float* __restrict__ cwf, const float* __restrict__ cbf,
    const float* __restrict__ cwb, const float* __restrict__ cbb,
    unsigned short* __restrict__ u, int ndir)
{
    int gid = blockIdx.x*blockDim.x + threadIdx.x;
    if (gid >= ndir*Mn*Din) return;
    int dir = gid / (Mn*Din);
    int rem = gid % (Mn*Din);
    int d = rem % Din, m = rem / Din;
    int l = m % Ln, b = m / Ln;
    const float* cw = dir ? cwb : cwf;
    const float* cb = dir ? cbb : cbf;
    float4 cwv = *(const float4*)(cw + d*4);
    float acc = cb[d];
    #pragma unroll
    for (int k = 0; k < 4; ++k) {
        int ls = l - 3 + k;
        if (ls < 0) continue;
        int lsrc = dir ? (Ln - 1 - ls) : ls;
        float cwk = (k==0)?cwv.x:(k==1)?cwv.y:(k==2)?cwv.z:cwv.w;
        acc = fmaf(us2f(xz[(size_t)(b*Ln + lsrc)*1536 + d]), cwk, acc);
    }
    u[gid] = f2us(siluf(acc));
}

__global__ __launch_bounds__(256) void xproj_gemm(
    const unsigned short* __restrict__ u,
    const unsigned short* __restrict__ xwf, const unsigned short* __restrict__ xwb,
    float* __restrict__ xd)
{
    __shared__ unsigned short As[2][64][72];
    __shared__ unsigned short Bs[2][64][72];
    int n0d, m0;
    xcd_tile((Mn + 63) >> 6, n0d, m0);
    int dir = n0d >> 6;
    const unsigned short* A = u + (size_t)dir*Mn*Din;
    const unsigned short* W = dir ? xwb : xwf;
    float* C = xd + (size_t)dir*Mn*40;
    int tid = threadIdx.x;
    int wave = tid >> 6, lane = tid & 63;
    int quad = lane >> 4, fr = lane & 15;
    int arow = tid >> 2;
    int c8   = (tid & 3) << 3;
    int mg = m0 + arow; if (mg >= Mn) mg = Mn - 1;
    int wrow = arow < 40 ? arow : 39;
    f32x4 acc[4] = {};
    {
        bf16x8 a0 = *(const bf16x8*)(A + (size_t)mg*Din + c8);
        bf16x8 a1 = *(const bf16x8*)(A + (size_t)mg*Din + c8 + 32);
        bf16x8 w0 = *(const bf16x8*)(W + (size_t)wrow*Din + c8);
        bf16x8 w1 = *(const bf16x8*)(W + (size_t)wrow*Din + c8 + 32);
        *(bf16x8*)&As[0][arow][c8]      = a0;
        *(bf16x8*)&As[0][arow][c8 + 32] = a1;
        *(bf16x8*)&Bs[0][arow][c8]      = w0;
        *(bf16x8*)&Bs[0][arow][c8 + 32] = w1;
    }
    int cur = 0;
    for (int k0 = 64; k0 <= Din; k0 += 64) {
        bool more = (k0 < Din);
        bf16x8 a0, a1, w0, w1;
        if (more) {
            a0 = *(const bf16x8*)(A + (size_t)mg*Din + k0 + c8);
            a1 = *(const bf16x8*)(A + (size_t)mg*Din + k0 + c8 + 32);
            w0 = *(const bf16x8*)(W + (size_t)wrow*Din + k0 + c8);
            w1 = *(const bf16x8*)(W + (size_t)wrow*Din + k0 + c8 + 32);
        }
        __syncthreads();
        bf16x8 af0 = *(const bf16x8*)&As[cur][wave*16 + fr][quad << 3];
        bf16x8 af1 = *(const bf16x8*)&As[cur][wave*16 + fr][(quad << 3) + 32];
        #pragma unroll
        for (int nt = 0; nt < 4; ++nt) {
            bf16x8 b0 = *(const bf16x8*)&Bs[cur][nt*16 + fr][quad << 3];
            bf16x8 b1 = *(const bf16x8*)&Bs[cur][nt*16 + fr][(quad << 3) + 32];
            acc[nt] = __builtin_amdgcn_mfma_f32_16x16x32_bf16(af0, b0, acc[nt], 0, 0, 0);
            acc[nt] = __builtin_amdgcn_mfma_f32_16x16x32_bf16(af1, b1, acc[nt], 0, 0, 0);
        }
        if (more) {
            *(bf16x8*)&As[cur^1][arow][c8]      = a0;
            *(bf16x8*)&As[cur^1][arow][c8 + 32] = a1;
            *(bf16x8*)&Bs[cur^1][arow][c8]      = w0;
            *(bf16x8*)&Bs[cur^1][arow][c8 + 32] = w1;
            cur ^= 1;
        }
    }
    #pragma unroll
    for (int nt = 0; nt < 4; ++nt) {
        int col = nt*16 + fr;
        if (col >= 40) continue;
        #pragma unroll
        for (int r = 0; r < 4; ++r) {
            int mgo = m0 + wave*16 + quad*4 + r;
            if (mgo < Mn) C[(size_t)mgo*40 + col] = acc[nt][r];
        }
    }
}

__global__ __launch_bounds__(256) void scanA(
    const unsigned short* __restrict__ u, const float* __restrict__ xd,
    const float* __restrict__ dwf, const float* __restrict__ dbf,
    const float* __restrict__ dwb, const float* __restrict__ dbb,
    const float* __restrict__ Alf, const float* __restrict__ Alb,
    float* __restrict__ Hsum, float* __restrict__ dtsum, int ndir)
{
    int gid = blockIdx.x*blockDim.x + threadIdx.x;
    if (gid >= ndir*Bn*NC*Din) return;
    int dir = gid / (Bn*NC*Din);
    int rem = gid % (Bn*NC*Din);
    int d = rem % Din;
    int bc = rem / Din;
    int c = bc % NC, b = bc / NC;
    const float* A_log = dir ? Alb : Alf;
    const float* dw = dir ? dwb : dwf;
    const float* db = dir ? dbb : dbf;
    float A[Sn];
    #pragma unroll
    for (int s = 0; s < Sn; ++s) A[s] = -__expf(A_log[d*Sn + s]);
    float dwr[Rn];
    #pragma unroll
    for (int r = 0; r < Rn; ++r) dwr[r] = dw[d*Rn + r];
    float dbv = db[d];
    float hs[Sn] = {0,0,0,0,0,0,0,0};
    float sdt = 0.f;
    int l0 = c*CL;
    const unsigned short* up = u + (size_t)dir*Mn*Din + ((size_t)b*Ln + l0)*Din + d;
    const float* xp = xd + (size_t)dir*Mn*40 + ((size_t)b*Ln + l0)*40;
    #pragma unroll
    for (int l = 0; l < CL; ++l) {
        float uv = us2f(up[(size_t)l*Din]);
        const float* xr = xp + l*40;
        float dta = dbv;
        #pragma unroll
        for (int r = 0; r < Rn; ++r) dta = fmaf(xr[r], dwr[r], dta);
        float dtv = (dta > 20.f) ? dta : log1pf(__expf(dta));
        sdt += dtv;
        const float4* B4 = (const float4*)(xr + Rn);
        float4 Bv0 = B4[0], Bv1 = B4[1];
        float du = dtv * uv;
        hs[0] = fmaf(__expf(dtv*A[0]), hs[0], du*Bv0.x);
        hs[1] = fmaf(__expf(dtv*A[1]), hs[1], du*Bv0.y);
        hs[2] = fmaf(__expf(dtv*A[2]), hs[2], du*Bv0.z);
        hs[3] = fmaf(__expf(dtv*A[3]), hs[3], du*Bv0.w);
        hs[4] = fmaf(__expf(dtv*A[4]), hs[4], du*Bv1.x);
        hs[5] = fmaf(__expf(dtv*A[5]), hs[5], du*Bv1.y);
        hs[6] = fmaf(__expf(dtv*A[6]), hs[6], du*Bv1.z);
        hs[7] = fmaf(__expf(dtv*A[7]), hs[7], du*Bv1.w);
    }
    float4* Hp = (float4*)(Hsum + (size_t)gid*8);
    Hp[0] = make_float4(hs[0], hs[1], hs[2], hs[3]);
    Hp[1] = make_float4(hs[4], hs[5], hs[6], hs[7]);
    dtsum[gid] = sdt;
}

__global__ __launch_bounds__(256) void scanB(
    const float* __restrict__ Alf, const float* __restrict__ Alb,
    float* __restrict__ Hsum, const float* __restrict__ dtsum, int ndir)
{
    int gid = blockIdx.x*blockDim.x + threadIdx.x;
    if (gid >= ndir*Bn*Din*Sn) return;
    int s   = gid & 7;
    int rem = gid >> 3;
    int d   = rem % Din;
    int t   = rem / Din;
    int b   = t % Bn, dir = t / Bn;
    const float* A_log = dir ? Alb : Alf;
    float Av = -__expf(A_log[d*Sn + s]);
    float h = 0.f;
    size_t base = (size_t)dir*Bn*NC*Din + (size_t)b*NC*Din + d;
    float* Hp = Hsum + base*8 + s;
    const float* dp = dtsum + base;
    #pragma unroll 7
    for (int c = 0; c < NC; ++c) {
        size_t off = (size_t)c*Din;
        float H = Hp[off*8];
        float sdt = dp[off];
        Hp[off*8] = h;
        h = fmaf(__expf(Av*sdt), h, H);
    }
}

__global__ __launch_bounds__(256) void scanC(
    const unsigned short* __restrict__ u, const float* __restrict__ xd,
    const float* __restrict__ dwf, const float* __restrict__ dbf,
    const float* __restrict__ dwb, const float* __restrict__ dbb,
    const float* __restrict__ Alf, const float* __restrict__ Alb,
    const float* __restrict__ Dpf, const float* __restrict__ Dpb,
    const float* __restrict__ Hsum, unsigned short* __restrict__ yt, int ndir)
{
    int gid = blockIdx.x*blockDim.x + threadIdx.x;
    if (gid >= ndir*Bn*NC*Din) return;
    int dir = gid / (Bn*NC*Din);
    int rem = gid % (Bn*NC*Din);
    int d = rem % Din;
    int bc = rem / Din;
    int c = bc % NC, b = bc / NC;
    const float* A_log = dir ? Alb : Alf;
    const float* dw = dir ? dwb : dwf;
    const float* db = dir ? dbb : dbf;
    const float* Dp = dir ? Dpb : Dpf;
    float A[Sn];
    #pragma unroll
    for (int s = 0; s < Sn; ++s) A[s] = -__expf(A_log[d*Sn + s]);
    float dwr[Rn];
    #pragma unroll
    for (int r = 0; r < Rn; ++r) dwr[r] = dw[d*Rn + r];
    float dbv = db[d];
    const float4* hp = (const float4*)(Hsum + (size_t)gid*8);
    float4 h0 = hp[0], h1 = hp[1];
    float hs[Sn] = {h0.x, h0.y, h0.z, h0.w, h1.x, h1.y, h1.z, h1.w};
    float Dd = Dp[d];
    int l0 = c*CL;
    const unsigned short* up = u + (size_t)dir*Mn*Din + ((size_t)b*Ln + l0)*Din + d;
    const float* xp = xd + (size_t)dir*Mn*40 + ((size_t)b*Ln + l0)*40;
    unsigned short* yp = yt + (size_t)dir*Mn*Din + (size_t)b*Ln*Din + d;
    #pragma unroll
    for (int l = 0; l < CL; ++l) {
        int gl = l0 + l;
        float uv = us2f(up[(size_t)l*Din]);
        const float* xr = xp + l*40;
        float dta = dbv;
        #pragma unroll
        for (int r = 0; r < Rn; ++r) dta = fmaf(xr[r], dwr[r], dta);
        float dtv = (dta > 20.f) ? dta : log1pf(__expf(dta));
        const float4* B4 = (const float4*)(xr + Rn);
        float4 Bv0 = B4[0], Bv1 = B4[1], Cv0 = B4[2], Cv1 = B4[3];
        float du = dtv * uv;
        float yv = 0.f;
        hs[0] = fmaf(__expf(dtv*A[0]), hs[0], du*Bv0.x); yv = fmaf(hs[0], Cv0.x, yv);
        hs[1] = fmaf(__expf(dtv*A[1]), hs[1], du*Bv0.y); yv = fmaf(hs[1], Cv0.y, yv);
        hs[2] = fmaf(__expf(dtv*A[2]), hs[2], du*Bv0.z); yv = fmaf(hs[2], Cv0.z, yv);
        hs[3] = fmaf(__expf(dtv*A[3]), hs[3], du*Bv0.w); yv = fmaf(hs[3], Cv0.w, yv);
        hs[4] = fmaf(__expf(dtv*A[4]), hs[4], du*Bv1.x); yv = fmaf(hs[4], Cv1.x, yv);
        hs[5] = fmaf(__expf(dtv*A[5]), hs[5], du*Bv1.y); yv = fmaf(hs[5], Cv1.y, yv);
        hs[6] = fmaf(__expf(dtv*A[6]), hs[6], du*Bv1.z); yv = fmaf(hs[6], Cv1.z, yv);
        hs[7] = fmaf(__expf(dtv*A[7]), hs[7], du*Bv1.w); yv = fmaf(hs[7], Cv1.w, yv);
        yv = fmaf(uv, Dd, yv);
        int ol = dir ? (Ln - 1 - gl) : gl;
        yp[(size_t)ol*Din] = f2us(yv);
    }
}

// ------------------------- final rmsnorm (h + h2 + res), h2 = split-K partial
__global__ __launch_bounds__(256) void final_k(
    const float* __restrict__ h, const float* __restrict__ h2,
    const float* __restrict__ res, const float* __restrict__ w,
    float* __restrict__ out)
{
    int wid  = (blockIdx.x * blockDim.x + threadIdx.x) >> 6;
    int lane = threadIdx.x & 63;
    if (wid >= Mn) return;
    const float* hp = h + (size_t)wid*En;
    const float* h2p = h2 + (size_t)wid*En;
    const float* rp = res + (size_t)wid*En;
    float v[6]; float ss = 0.f;
    #pragma unroll
    for (int j = 0; j < 6; ++j) {
        int e = lane + j*64;
        float r = hp[e] + h2p[e] + rp[e];
        v[j] = r; ss = fmaf(r, r, ss);
    }
    #pragma unroll
    for (int off = 32; off; off >>= 1) ss += __shfl_xor(ss, off, 64);
    float scale = rsqrtf(ss * (1.f/(float)En) + 1e-5f);
    #pragma unroll
    for (int j = 0; j < 6; ++j) {
        int e = lane + j*64;
        out[(size_t)wid*En + e] = v[j] * scale * w[e];
    }
}

extern "C" void kernel_launch(void* const* d_in, const int* in_sizes, int n_in,
                              void* d_out, int out_size, void* d_ws, size_t ws_size,
                              hipStream_t stream)
{
    const float* x         = (const float*)d_in[0];
    const float* patch_w   = (const float*)d_in[1];
    const float* patch_b   = (const float*)d_in[2];
    const float* pos_embed = (const float*)d_in[3];
    const float* in_proj_w = (const float*)d_in[4];
    const float* conv_w    = (const float*)d_in[5];
    const float* conv_b    = (const float*)d_in[6];
    const float* xproj_w   = (const float*)d_in[7];
    const float* dtproj_w  = (const float*)d_in[8];
    const float* dtproj_b  = (const float*)d_in[9];
    const float* A_log     = (const float*)d_in[10];
    const float* D_param   = (const float*)d_in[11];
    const float* outproj_w = (const float*)d_in[12];
    const float* norm_w    = (const float*)d_in[13];
    const float* conv_wb   = (const float*)d_in[14];
    const float* conv_bb   = (const float*)d_in[15];
    const float* xproj_wb  = (const float*)d_in[16];
    const float* dtproj_wb = (const float*)d_in[17];
    const float* dtproj_bb = (const float*)d_in[18];
    const float* A_log_b   = (const float*)d_in[19];
    const float* D_b       = (const float*)d_in[20];
    const float* norm_f_w  = (const float*)d_in[21];

    // ---- carve (~56 MB; ws ~268 MB per fillBuffer WRITE_SIZE evidence)
    float* pf   = (float*)d_ws;
    float* h    = pf;  pf += (size_t)Mn*En;
    float* h2   = pf;  pf += (size_t)Mn*En;            // split-K partial (z=1)
    float* res  = pf;  pf += (size_t)Mn*En;
    float* xd   = pf;  pf += (size_t)2*Mn*40;          // [dir][m][40]
    float* Hsum = pf;  pf += (size_t)2*Bn*NC*Din*Sn;   // [dir][b][c][d][8]
    float* dtsm = pf;  pf += (size_t)2*Bn*NC*Din;
    unsigned short* ub = (unsigned short*)pf;
    unsigned short* xz = ub;  ub += (size_t)Mn*1536;
    unsigned short* u  = ub;  ub += (size_t)2*Mn*Din;   // [dir][m][d]; hn overlays
    unsigned short* hn = u;
    unsigned short* yt = ub;  ub += (size_t)2*Mn*Din;   // [dir][m][d]
    unsigned short* w_in = ub;  ub += (size_t)NW0;      // bf16 weights
    unsigned short* w_out= ub;  ub += (size_t)NW1;
    unsigned short* w_xf = ub;  ub += (size_t)NW2;
    unsigned short* w_xb = ub;  ub += (size_t)NW3;
    unsigned short* w_pm = ub;  ub += (size_t)NW4;
    unsigned short* pm = (unsigned short*)Hsum;         // overlay: pre-loop only
    size_t needed = (size_t)((char*)ub - (char*)d_ws);
    if (ws_size < needed) return;

    const int wave_blocks = (Mn*64)/256;             // 392
    const int B_me   = (Mn*En + 255)/256;
    const int B_md   = (Mn*768 + 255)/256;           // 4704
    const int B_cw   = ((NW0+NW1+NW2+NW3+NW4)/4 + 255)/256;
    const int mTiles = (Mn + 63)/64;                 // 25

    // ---- weight pre-cast + patch embed (patch GEMM split-K x2: h, h2)
    k_castw<<<B_cw, 256, 0, stream>>>(in_proj_w, outproj_w, xproj_w, xproj_wb,
                                      patch_w, w_in, w_out, w_xf, w_xb, w_pm);
    k_patch<<<B_md, 256, 0, stream>>>(x, pm);
    dim3 g0((En/64)*2, mTiles);
    gemm_mfma<float,0,2><<<g0, 256, 0, stream>>>(pm, nullptr, nullptr, w_pm,
                                                 h, En, Mn, En, 768, 1);
    k_posadd<<<B_me, 256, 0, stream>>>(h, h2, patch_b, pos_embed);

    for (int i = 0; i < DEPTH; ++i) {
        int ndir = (i < NSPA) ? 2 : 1;
        rms_residual<<<wave_blocks, 256, 0, stream>>>(h, h2, res, hn,
                                                      norm_w + (size_t)i*En, i == 0);

        dim3 g1(1536/64, mTiles);
        gemm_mfma<unsigned short,0,1><<<g1, 256, 0, stream>>>(
            hn, nullptr, nullptr, w_in + (size_t)i*1536*En,
            xz, 1536, Mn, 1536, En, 1);

        const float* cwf = conv_w + (size_t)i*Din*4;
        const float* cbf = conv_b + (size_t)i*Din;
        const float* dwf = dtproj_w + (size_t)i*Din*Rn;
        const float* dbf = dtproj_b + (size_t)i*Din;
        const float* Alf = A_log + (size_t)i*Din*Sn;
        const float* Dpf = D_param + (size_t)i*Din;
        const float* cwb = conv_wb + (size_t)i*Din*4;
        const float* cbb = conv_bb + (size_t)i*Din;
        const float* dwb = dtproj_wb + (size_t)i*Din*Rn;
        const float* dbb = dtproj_bb + (size_t)i*Din;
        const float* Alb = A_log_b + (size_t)i*Din*Sn;
        const float* Dpb = D_b + (size_t)i*Din;
        const unsigned short* xwf = w_xf + (size_t)i*40*Din;
        const unsigned short* xwb = w_xb + (size_t)i*40*Din;

        CoopP cp;
        cp.xz = xz; cp.cwf = cwf; cp.cbf = cbf; cp.cwb = cwb; cp.cbb = cbb;
        cp.xwf = xwf; cp.xwb = xwb; cp.u = u; cp.xd = xd;
        cp.dwf = dwf; cp.dbf = dbf; cp.dwb = dwb; cp.dbb = dbb;
        cp.Alf = Alf; cp.Alb = Alb; cp.Dpf = Dpf; cp.Dpb = Dpb;
        cp.Hsum = Hsum; cp.dtsum = dtsm; cp.yt = yt; cp.ndir = ndir;
        void* cargs[] = { &cp };
        hipError_t cerr = hipLaunchCooperativeKernel(
            (const void*)coop_scan, dim3(768), dim3(256), cargs, 0, stream);
        if (cerr != hipSuccess) {
            // legacy 5-kernel fallback (bit-identical math)
            int c_blocks  = (ndir*Mn*Din + 255)/256;
            int sA_blocks = (ndir*Bn*NC*Din + 255)/256;
            int sB_blocks = (ndir*Bn*Din*Sn + 255)/256;
            k_conv2<<<c_blocks, 256, 0, stream>>>(xz, cwf, cbf, cwb, cbb, u, ndir);
            dim3 gx(ndir, mTiles);
            xproj_gemm<<<gx, 256, 0, stream>>>(u, xwf, xwb, xd);
            scanA<<<sA_blocks, 256, 0, stream>>>(u, xd, dwf, dbf, dwb, dbb,
                                                 Alf, Alb, Hsum, dtsm, ndir);
            scanB<<<sB_blocks, 256, 0, stream>>>(Alf, Alb, Hsum, dtsm, ndir);
            scanC<<<sA_blocks, 256, 0, stream>>>(u, xd, dwf, dbf, dwb, dbb,
                                                 Alf, Alb, Dpf, Dpb, Hsum, yt, ndir);
        }

        dim3 g2((En/64)*2, mTiles);
        gemm_mfma<float,1,2><<<g2, 256, 0, stream>>>(
            yt, yt + (size_t)Mn*Din, xz + Din, w_out + (size_t)i*En*Din,
            h, En, Mn, En, Din, ndir);
    }

    final_k<<<wave_blocks, 256, 0, stream>>>(h, h2, res, norm_f_w, (float*)d_out);
}

// Round 10
// 3283.466 us; speedup vs baseline: 1.7065x; 1.7065x over previous
//
#include <hip/hip_runtime.h>
#include <hip/hip_bf16.h>
#include <hip/hip_cooperative_groups.h>
#include <math.h>

// EndoMamba r23: coop fusion, deadlock-proofed.
// r21: (256,4) cap -> 64 VGPR -> 40MB/launch scratch spills (440us).
// r22: no cap -> likely >128 VGPR -> 768-block coop grid exceeded residency
//      -> grid.sync deadlock under graph capture -> harness timeout.
// Fix: __launch_bounds__(256,2) (128-VGPR cap, no spills expected) + grid
// sized from an occupancy query (<= capacity, <= 768); all phases are
// grid-strided so any grid is correct. Fallback = r20b 5-kernel path.
#define Bn   2
#define Tn   4
#define Nn   196
#define Ln   784
#define Mn   1568
#define En   384
#define Din  768
#define Sn   8
#define Rn   24
#define DEPTH 12
#define NSPA 6
#define NC   98
#define CL   8      // 784 = 98*8

typedef __attribute__((ext_vector_type(8))) short bf16x8;
typedef __attribute__((ext_vector_type(4))) float f32x4;

__device__ __forceinline__ float siluf(float v) { return v / (1.f + __expf(-v)); }
__device__ __forceinline__ float us2f(unsigned short u) {
    union { unsigned int i; float f; } v; v.i = (unsigned)u << 16; return v.f;
}
__device__ __forceinline__ unsigned short f2us(float f) {
    __hip_bfloat16 b = __float2bfloat16(f);
    return *(unsigned short*)&b;
}
__device__ __forceinline__ void cstore(float* p, float v) { *p = v; }
__device__ __forceinline__ void cstore(unsigned short* p, float v) { *p = f2us(v); }

// bijective XCD swizzle (m204): consecutive flats within an XCD share n-tile
__device__ __forceinline__ void xcd_tile(int ny, int& n0, int& m0)
{
    int nx = gridDim.x;
    int total = nx*ny;
    int bid = blockIdx.y*nx + blockIdx.x;
    int q = total >> 3, r = total & 7;
    int xcd = bid & 7, idx = bid >> 3;
    int base = (xcd < r) ? xcd*(q+1) : r*(q+1) + (xcd - r)*q;
    int flat = base + idx;
    n0 = (flat / ny) * 64;
    m0 = (flat % ny) * 64;
}

// -------------------- weight pre-cast fp32 -> bf16 (once per launch)
#define NW0 7077888   // in_proj 12*1536*384
#define NW1 3538944   // outproj 12*384*768
#define NW2 368640    // xproj fwd 12*40*768
#define NW3 184320    // xproj bwd 6*40*768
#define NW4 294912    // patch 384*768
__device__ __forceinline__ void cast4(unsigned short* d, const float* s)
{
    float4 v = *(const float4*)s;
    ushort4 o;
    o.x = f2us(v.x); o.y = f2us(v.y); o.z = f2us(v.z); o.w = f2us(v.w);
    *(ushort4*)d = o;
}
__global__ __launch_bounds__(256) void k_castw(
    const float* __restrict__ w0, const float* __restrict__ w1,
    const float* __restrict__ w2, const float* __restrict__ w3,
    const float* __restrict__ w4,
    unsigned short* __restrict__ o0, unsigned short* __restrict__ o1,
    unsigned short* __restrict__ o2, unsigned short* __restrict__ o3,
    unsigned short* __restrict__ o4)
{
    int i4 = (blockIdx.x*blockDim.x + threadIdx.x)*4;
    if (i4 < NW0) { cast4(o0+i4, w0+i4); return; }
    i4 -= NW0;
    if (i4 < NW1) { cast4(o1+i4, w1+i4); return; }
    i4 -= NW1;
    if (i4 < NW2) { cast4(o2+i4, w2+i4); return; }
    i4 -= NW2;
    if (i4 < NW3) { cast4(o3+i4, w3+i4); return; }
    i4 -= NW3;
    if (i4 < NW4) { cast4(o4+i4, w4+i4); }
}

// ------------------------------------------- patch gather -> pm[m,768] bf16
__global__ __launch_bounds__(256) void k_patch(
    const float* __restrict__ x, unsigned short* __restrict__ pm)
{
    int gid = blockIdx.x*blockDim.x + threadIdx.x;
    if (gid >= Mn*768) return;
    int idx = gid % 768, token = gid / 768;
    int b = token / Ln, l = token % Ln;
    int t = l / Nn, n = l % Nn;
    int hh = n / 14, ww = n % 14;
    int c = idx >> 8, rem = idx & 255, p = rem >> 4, q = rem & 15;
    pm[gid] = f2us(x[(((size_t)(b*3 + c)*Tn + t)*224 + (hh*16 + p))*224 + (ww*16 + q)]);
}

// ---------------- embed epilogue: h = h + h2 + pb + pos + pe (split-K add)
__global__ __launch_bounds__(256) void k_posadd(
    float* __restrict__ h, const float* __restrict__ h2,
    const float* __restrict__ pb, const float* __restrict__ pos)
{
    int gid = blockIdx.x*blockDim.x + threadIdx.x;
    if (gid >= Mn*En) return;
    int e = gid % En, token = gid / En;
    int l = token % Ln;
    int t = l / Nn, n = l % Nn;
    float div = __expf(-logf(10000.f) * (float)(e & ~1) / (float)En);
    float ang = (float)t * div;
    h[gid] += h2[gid] + pb[e] + pos[n*En + e] + ((e & 1) ? cosf(ang) : sinf(ang));
}

// -------------------- rmsnorm (+ residual); h2 = split-K partial of out_proj
__global__ __launch_bounds__(256) void rms_residual(
    const float* __restrict__ hin, const float* __restrict__ h2,
    float* __restrict__ res, unsigned short* __restrict__ hn,
    const float* __restrict__ w, int first)
{
    int wid  = (blockIdx.x * blockDim.x + threadIdx.x) >> 6;   // token
    int lane = threadIdx.x & 63;
    if (wid >= Mn) return;
    const float* hp = hin + (size_t)wid*En;
    const float* h2p = h2 + (size_t)wid*En;
    float* rp = res + (size_t)wid*En;
    float v[6]; float ss = 0.f;
    #pragma unroll
    for (int j = 0; j < 6; ++j) {
        int e = lane + j*64;
        float r = first ? hp[e] : (hp[e] + h2p[e] + rp[e]);
        v[j] = r; ss = fmaf(r, r, ss);
    }
    #pragma unroll
    for (int off = 32; off; off >>= 1) ss += __shfl_xor(ss, off, 64);
    float scale = rsqrtf(ss * (1.f/(float)En) + 1e-5f);
    #pragma unroll
    for (int j = 0; j < 6; ++j) {
        int e = lane + j*64;
        rp[e] = v[j];
        hn[(size_t)wid*En + e] = f2us(v[j] * scale * w[e]);
    }
}

// ---------------- bf16 MFMA GEMM: C = A[M,K] * Wb[N,K]^T, Wb bf16 (pre-cast)
// BK=64 double-buffered, one barrier per step, XCD-swizzled tiles.
// SK: split-K factor; z-th partial written to C + z*M*ldc.
// GATED: A_eff = (yf + (ndir==2? yb:0)) * silu(z), all bf16 inputs.
template<typename CT, int GATED, int SK>
__global__ __launch_bounds__(256) void gemm_mfma(
    const unsigned short* __restrict__ A,     // bf16 A (or yf when GATED)
    const unsigned short* __restrict__ Yb,    // yb (GATED only)
    const unsigned short* __restrict__ Z,     // z base, row stride 1536 (GATED)
    const unsigned short* __restrict__ Wb,    // bf16 W [N][K]
    CT* __restrict__ C, int ldc, int M, int N, int K, int ndir)
{
    __shared__ unsigned short As[2][64][72];   // 64 k + 8 pad
    __shared__ unsigned short Bs[2][64][72];
    int n0, m0;
    xcd_tile((M + 63) >> 6, n0, m0);
    int nidx = n0 >> 6;
    int zk = nidx % SK;
    n0 = (nidx / SK) * 64;
    int kbeg = zk * (K / SK);
    int kend = kbeg + K / SK;
    CT* Cz = C + (size_t)zk*M*ldc;
    int tid = threadIdx.x;
    int wave = tid >> 6, lane = tid & 63;
    int quad = lane >> 4, fr = lane & 15;
    int arow = tid >> 2;            // 0..63
    int c8   = (tid & 3) << 3;      // 0,8,16,24
    int mg = m0 + arow; if (mg >= M) mg = M - 1;
    f32x4 acc[4] = {};

    auto gate8 = [&](const unsigned short* yf, const unsigned short* yb,
                     const unsigned short* zp) -> bf16x8 {
        bf16x8 f = *(const bf16x8*)yf;
        bf16x8 bb = *(const bf16x8*)yb;
        bf16x8 zz = *(const bf16x8*)zp;
        unsigned short o[8];
        const unsigned short* fu = (const unsigned short*)&f;
        const unsigned short* bu = (const unsigned short*)&bb;
        const unsigned short* zu = (const unsigned short*)&zz;
        #pragma unroll
        for (int j = 0; j < 8; ++j) {
            float v = us2f(fu[j]);
            if (ndir == 2) v += us2f(bu[j]);
            o[j] = f2us(v * siluf(us2f(zu[j])));
        }
        return *(bf16x8*)o;
    };

    auto load_tile = [&](int k0, bf16x8& av0, bf16x8& av1,
                         bf16x8& wv0, bf16x8& wv1) {
        if (!GATED) {
            av0 = *(const bf16x8*)(A + (size_t)mg*K + k0 + c8);
            av1 = *(const bf16x8*)(A + (size_t)mg*K + k0 + c8 + 32);
        } else {
            size_t ro = (size_t)mg*K + k0 + c8;
            size_t zo = (size_t)mg*1536 + k0 + c8;
            av0 = gate8(A + ro, Yb + ro, Z + zo);
            av1 = gate8(A + ro + 32, Yb + ro + 32, Z + zo + 32);
        }
        wv0 = *(const bf16x8*)(Wb + (size_t)(n0 + arow)*K + k0 + c8);
        wv1 = *(const bf16x8*)(Wb + (size_t)(n0 + arow)*K + k0 + c8 + 32);
    };

    {   // prologue: stage first k-tile into buffer 0
        bf16x8 a0, a1, w0, w1;
        load_tile(kbeg, a0, a1, w0, w1);
        *(bf16x8*)&As[0][arow][c8]      = a0;
        *(bf16x8*)&As[0][arow][c8 + 32] = a1;
        *(bf16x8*)&Bs[0][arow][c8]      = w0;
        *(bf16x8*)&Bs[0][arow][c8 + 32] = w1;
    }
    int cur = 0;
    for (int k0 = kbeg + 64; k0 <= kend; k0 += 64) {
        bool more = (k0 < kend);
        bf16x8 a0, a1, w0, w1;
        if (more) load_tile(k0, a0, a1, w0, w1);   // issue loads before barrier
        __syncthreads();
        bf16x8 af0 = *(const bf16x8*)&As[cur][wave*16 + fr][quad << 3];
        bf16x8 af1 = *(const bf16x8*)&As[cur][wave*16 + fr][(quad << 3) + 32];
        #pragma unroll
        for (int nt = 0; nt < 4; ++nt) {
            bf16x8 b0 = *(const bf16x8*)&Bs[cur][nt*16 + fr][quad << 3];
            bf16x8 b1 = *(const bf16x8*)&Bs[cur][nt*16 + fr][(quad << 3) + 32];
            acc[nt] = __builtin_amdgcn_mfma_f32_16x16x32_bf16(af0, b0, acc[nt], 0, 0, 0);
            acc[nt] = __builtin_amdgcn_mfma_f32_16x16x32_bf16(af1, b1, acc[nt], 0, 0, 0);
        }
        if (more) {
            *(bf16x8*)&As[cur^1][arow][c8]      = a0;
            *(bf16x8*)&As[cur^1][arow][c8 + 32] = a1;
            *(bf16x8*)&Bs[cur^1][arow][c8]      = w0;
            *(bf16x8*)&Bs[cur^1][arow][c8 + 32] = w1;
            cur ^= 1;
        }
    }
    #pragma unroll
    for (int nt = 0; nt < 4; ++nt) {
        #pragma unroll
        for (int r = 0; r < 4; ++r) {
            int mgo = m0 + wave*16 + quad*4 + r;
            if (mgo < M) cstore(Cz + (size_t)mgo*ldc + n0 + nt*16 + fr, acc[nt][r]);
        }
    }
}

// ---------------------- parameters for the fused cooperative SSM-middle
struct CoopP {
    const unsigned short* xz;
    const float *cwf, *cbf, *cwb, *cbb;
    const unsigned short *xwf, *xwb;
    unsigned short* u;
    float* xd;
    const float *dwf, *dbf, *dwb, *dbb, *Alf, *Alb, *Dpf, *Dpb;
    float *Hsum, *dtsum;
    unsigned short* yt;
    int ndir;
};

// One cooperative launch per layer: conv -> xproj(MFMA) -> scanA -> scanB ->
// scanC with grid.sync between phases. Per-item math identical to the legacy
// kernels (bit-identical results). (256,2): 128-VGPR cap (no spills; r21's
// 64-cap spilled) and >=2 blocks/CU guaranteed; grid is sized to occupancy
// by the host so grid.sync can never deadlock.
__global__ __launch_bounds__(256, 2) void coop_scan(CoopP p)
{
    namespace cg = cooperative_groups;
    cg::grid_group grid = cg::this_grid();
    __shared__ unsigned short As[2][64][72];
    __shared__ unsigned short Bs[2][64][72];
    int tid = threadIdx.x;
    int gid0 = blockIdx.x*blockDim.x + tid;
    int gstride = gridDim.x*blockDim.x;

    // ---------------- P0: u = silu(conv(xz))
    for (int gid = gid0; gid < p.ndir*Mn*Din; gid += gstride) {
        int dir = gid / (Mn*Din);
        int rem = gid % (Mn*Din);
        int d = rem % Din, m = rem / Din;
        int l = m % Ln, b = m / Ln;
        const float* cw = dir ? p.cwb : p.cwf;
        const float* cb = dir ? p.cbb : p.cbf;
        float4 cwv = *(const float4*)(cw + d*4);
        float acc = cb[d];
        #pragma unroll
        for (int k = 0; k < 4; ++k) {
            int ls = l - 3 + k;
            if (ls < 0) continue;
            int lsrc = dir ? (Ln - 1 - ls) : ls;
            float cwk = (k==0)?cwv.x:(k==1)?cwv.y:(k==2)?cwv.z:cwv.w;
            acc = fmaf(us2f(p.xz[(size_t)(b*Ln + lsrc)*1536 + d]), cwk, acc);
        }
        p.u[gid] = f2us(siluf(acc));
    }
    grid.sync();

    // ---------------- P1: xd = u * xw^T (MFMA, 64-wide N-tile)
    for (int tile = blockIdx.x; tile < p.ndir*25; tile += gridDim.x) {
        int dir = tile / 25;
        int m0 = (tile % 25) * 64;
        const unsigned short* A = p.u + (size_t)dir*Mn*Din;
        const unsigned short* W = dir ? p.xwb : p.xwf;
        float* C = p.xd + (size_t)dir*Mn*40;
        int wave = tid >> 6, lane = tid & 63;
        int quad = lane >> 4, fr = lane & 15;
        int arow = tid >> 2;
        int c8   = (tid & 3) << 3;
        int mg = m0 + arow; if (mg >= Mn) mg = Mn - 1;
        int wrow = arow < 40 ? arow : 39;
        f32x4 acc[4] = {};
        {
            bf16x8 a0 = *(const bf16x8*)(A + (size_t)mg*Din + c8);
            bf16x8 a1 = *(const bf16x8*)(A + (size_t)mg*Din + c8 + 32);
            bf16x8 w0 = *(const bf16x8*)(W + (size_t)wrow*Din + c8);
            bf16x8 w1 = *(const bf16x8*)(W + (size_t)wrow*Din + c8 + 32);
            *(bf16x8*)&As[0][arow][c8]      = a0;
            *(bf16x8*)&As[0][arow][c8 + 32] = a1;
            *(bf16x8*)&Bs[0][arow][c8]      = w0;
            *(bf16x8*)&Bs[0][arow][c8 + 32] = w1;
        }
        int cur = 0;
        for (int k0 = 64; k0 <= Din; k0 += 64) {
            bool more = (k0 < Din);
            bf16x8 a0, a1, w0, w1;
            if (more) {
                a0 = *(const bf16x8*)(A + (size_t)mg*Din + k0 + c8);
                a1 = *(const bf16x8*)(A + (size_t)mg*Din + k0 + c8 + 32);
                w0 = *(const bf16x8*)(W + (size_t)wrow*Din + k0 + c8);
                w1 = *(const bf16x8*)(W + (size_t)wrow*Din + k0 + c8 + 32);
            }
            __syncthreads();
            bf16x8 af0 = *(const bf16x8*)&As[cur][wave*16 + fr][quad << 3];
            bf16x8 af1 = *(const bf16x8*)&As[cur][wave*16 + fr][(quad << 3) + 32];
            #pragma unroll
            for (int nt = 0; nt < 4; ++nt) {
                bf16x8 b0 = *(const bf16x8*)&Bs[cur][nt*16 + fr][quad << 3];
                bf16x8 b1 = *(const bf16x8*)&Bs[cur][nt*16 + fr][(quad << 3) + 32];
                acc[nt] = __builtin_amdgcn_mfma_f32_16x16x32_bf16(af0, b0, acc[nt], 0, 0, 0);
                acc[nt] = __builtin_amdgcn_mfma_f32_16x16x32_bf16(af1, b1, acc[nt], 0, 0, 0);
            }
            if (more) {
                *(bf16x8*)&As[cur^1][arow][c8]      = a0;
                *(bf16x8*)&As[cur^1][arow][c8 + 32] = a1;
                *(bf16x8*)&Bs[cur^1][arow][c8]      = w0;
                *(bf16x8*)&Bs[cur^1][arow][c8 + 32] = w1;
                cur ^= 1;
            }
        }
        #pragma unroll
        for (int nt = 0; nt < 4; ++nt) {
            int col = nt*16 + fr;
            if (col >= 40) continue;
            #pragma unroll
            for (int r = 0; r < 4; ++r) {
                int mgo = m0 + wave*16 + quad*4 + r;
                if (mgo < Mn) C[(size_t)mgo*40 + col] = acc[nt][r];
            }
        }
        __syncthreads();   // LDS safe for potential next tile
    }
    grid.sync();

    // ---------------- P2: scanA (per-chunk Sdt, H[8])
    for (int gid = gid0; gid < p.ndir*Bn*NC*Din; gid += gstride) {
        int dir = gid / (Bn*NC*Din);
        int rem = gid % (Bn*NC*Din);
        int d = rem % Din;
        int bc = rem / Din;
        int c = bc % NC, b = bc / NC;
        const float* A_log = dir ? p.Alb : p.Alf;
        const float* dw = dir ? p.dwb : p.dwf;
        const float* db = dir ? p.dbb : p.dbf;
        float A[Sn];
        #pragma unroll
        for (int s = 0; s < Sn; ++s) A[s] = -__expf(A_log[d*Sn + s]);
        float dwr[Rn];
        #pragma unroll
        for (int r = 0; r < Rn; ++r) dwr[r] = dw[d*Rn + r];
        float dbv = db[d];
        float hs[Sn] = {0,0,0,0,0,0,0,0};
        float sdt = 0.f;
        int l0 = c*CL;
        const unsigned short* up = p.u + (size_t)dir*Mn*Din + ((size_t)b*Ln + l0)*Din + d;
        const float* xp = p.xd + (size_t)dir*Mn*40 + ((size_t)b*Ln + l0)*40;
        #pragma unroll
        for (int l = 0; l < CL; ++l) {
            float uv = us2f(up[(size_t)l*Din]);
            const float* xr = xp + l*40;
            float dta = dbv;
            #pragma unroll
            for (int r = 0; r < Rn; ++r) dta = fmaf(xr[r], dwr[r], dta);
            float dtv = (dta > 20.f) ? dta : log1pf(__expf(dta));
            sdt += dtv;
            const float4* B4 = (const float4*)(xr + Rn);
            float4 Bv0 = B4[0], Bv1 = B4[1];
            float du = dtv * uv;
            hs[0] = fmaf(__expf(dtv*A[0]), hs[0], du*Bv0.x);
            hs[1] = fmaf(__expf(dtv*A[1]), hs[1], du*Bv0.y);
            hs[2] = fmaf(__expf(dtv*A[2]), hs[2], du*Bv0.z);
            hs[3] = fmaf(__expf(dtv*A[3]), hs[3], du*Bv0.w);
            hs[4] = fmaf(__expf(dtv*A[4]), hs[4], du*Bv1.x);
            hs[5] = fmaf(__expf(dtv*A[5]), hs[5], du*Bv1.y);
            hs[6] = fmaf(__expf(dtv*A[6]), hs[6], du*Bv1.z);
            hs[7] = fmaf(__expf(dtv*A[7]), hs[7], du*Bv1.w);
        }
        float4* Hp = (float4*)(p.Hsum + (size_t)gid*8);
        Hp[0] = make_float4(hs[0], hs[1], hs[2], hs[3]);
        Hp[1] = make_float4(hs[4], hs[5], hs[6], hs[7]);
        p.dtsum[gid] = sdt;
    }
    grid.sync();

    // ---------------- P3: scanB serial fixup in-place on Hsum
    for (int gid = gid0; gid < p.ndir*Bn*Din*Sn; gid += gstride) {
        int s   = gid & 7;
        int rem = gid >> 3;
        int d   = rem % Din;
        int t   = rem / Din;
        int b   = t % Bn, dir = t / Bn;
        const float* A_log = dir ? p.Alb : p.Alf;
        float Av = -__expf(A_log[d*Sn + s]);
        float h = 0.f;
        size_t base = (size_t)dir*Bn*NC*Din + (size_t)b*NC*Din + d;
        float* Hp = p.Hsum + base*8 + s;
        const float* dp = p.dtsum + base;
        #pragma unroll 7
        for (int c = 0; c < NC; ++c) {
            size_t off = (size_t)c*Din;
            float H = Hp[off*8];
            float sdt = dp[off];
            Hp[off*8] = h;
            h = fmaf(__expf(Av*sdt), h, H);
        }
    }
    grid.sync();

    // ---------------- P4: scanC seeded local scan, raw y emit
    for (int gid = gid0; gid < p.ndir*Bn*NC*Din; gid += gstride) {
        int dir = gid / (Bn*NC*Din);
        int rem = gid % (Bn*NC*Din);
        int d = rem % Din;
        int bc = rem / Din;
        int c = bc % NC, b = bc / NC;
        const float* A_log = dir ? p.Alb : p.Alf;
        const float* dw = dir ? p.dwb : p.dwf;
        const float* db = dir ? p.dbb : p.dbf;
        const float* Dp = dir ? p.Dpb : p.Dpf;
        float A[Sn];
        #pragma unroll
        for (int s = 0; s < Sn; ++s) A[s] = -__expf(A_log[d*Sn + s]);
        float dwr[Rn];
        #pragma unroll
        for (int r = 0; r < Rn; ++r) dwr[r] = dw[d*Rn + r];
        float dbv = db[d];
        const float4* hp = (const float4*)(p.Hsum + (size_t)gid*8);
        float4 h0 = hp[0], h1 = hp[1];
        float hs[Sn] = {h0.x, h0.y, h0.z, h0.w, h1.x, h1.y, h1.z, h1.w};
        float Dd = Dp[d];
        int l0 = c*CL;
        const unsigned short* up = p.u + (size_t)dir*Mn*Din + ((size_t)b*Ln + l0)*Din + d;
        const float* xp = p.xd + (size_t)dir*Mn*40 + ((size_t)b*Ln + l0)*40;
        unsigned short* yp = p.yt + (size_t)dir*Mn*Din + (size_t)b*Ln*Din + d;
        #pragma unroll
        for (int l = 0; l < CL; ++l) {
            int gl = l0 + l;
            float uv = us2f(up[(size_t)l*Din]);
            const float* xr = xp + l*40;
            float dta = dbv;
            #pragma unroll
            for (int r = 0; r < Rn; ++r) dta = fmaf(xr[r], dwr[r], dta);
            float dtv = (dta > 20.f) ? dta : log1pf(__expf(dta));
            const float4* B4 = (const float4*)(xr + Rn);
            float4 Bv0 = B4[0], Bv1 = B4[1], Cv0 = B4[2], Cv1 = B4[3];
            float du = dtv * uv;
            float yv = 0.f;
            hs[0] = fmaf(__expf(dtv*A[0]), hs[0], du*Bv0.x); yv = fmaf(hs[0], Cv0.x, yv);
            hs[1] = fmaf(__expf(dtv*A[1]), hs[1], du*Bv0.y); yv = fmaf(hs[1], Cv0.y, yv);
            hs[2] = fmaf(__expf(dtv*A[2]), hs[2], du*Bv0.z); yv = fmaf(hs[2], Cv0.z, yv);
            hs[3] = fmaf(__expf(dtv*A[3]), hs[3], du*Bv0.w); yv = fmaf(hs[3], Cv0.w, yv);
            hs[4] = fmaf(__expf(dtv*A[4]), hs[4], du*Bv1.x); yv = fmaf(hs[4], Cv1.x, yv);
            hs[5] = fmaf(__expf(dtv*A[5]), hs[5], du*Bv1.y); yv = fmaf(hs[5], Cv1.y, yv);
            hs[6] = fmaf(__expf(dtv*A[6]), hs[6], du*Bv1.z); yv = fmaf(hs[6], Cv1.z, yv);
            hs[7] = fmaf(__expf(dtv*A[7]), hs[7], du*Bv1.w); yv = fmaf(hs[7], Cv1.w, yv);
            yv = fmaf(uv, Dd, yv);
            int ol = dir ? (Ln - 1 - gl) : gl;
            yp[(size_t)ol*Din] = f2us(yv);
        }
    }
}

// ---------------------------------- legacy fallback kernels (r20b verbatim)
__global__ __launch_bounds__(256) void k_conv2(
    const unsigned short* __restrict__ xz,
    const float* __restrict__ cwf, const float* __restrict__ cbf,
    const float* __restrict__ cwb, const float* __restrict__ cbb,
    unsigned short* __restrict__ u, int ndir)
{
    int gid = blockIdx.x*blockDim.x + threadIdx.x;
    if (gid >= ndir*Mn*Din) return;
    int dir = gid / (Mn*Din);
    int rem = gid % (Mn*Din);
    int d = rem % Din, m = rem / Din;
    int l = m % Ln, b = m / Ln;
    const float* cw = dir ? cwb : cwf;
    const float* cb = dir ? cbb : cbf;
    float4 cwv = *(const float4*)(cw + d*4);
    float acc = cb[d];
    #pragma unroll
    for (int k = 0; k < 4; ++k) {
        int ls = l - 3 + k;
        if (ls < 0) continue;
        int lsrc = dir ? (Ln - 1 - ls) : ls;
        float cwk = (k==0)?cwv.x:(k==1)?cwv.y:(k==2)?cwv.z:cwv.w;
        acc = fmaf(us2f(xz[(size_t)(b*Ln + lsrc)*1536 + d]), cwk, acc);
    }
    u[gid] = f2us(siluf(acc));
}

__global__ __launch_bounds__(256) void xproj_gemm(
    const unsigned short* __restrict__ u,
    const unsigned short* __restrict__ xwf, const unsigned short* __restrict__ xwb,
    float* __restrict__ xd)
{
    __shared__ unsigned short As[2][64][72];
    __shared__ unsigned short Bs[2][64][72];
    int n0d, m0;
    xcd_tile((Mn + 63) >> 6, n0d, m0);
    int dir = n0d >> 6;
    const unsigned short* A = u + (size_t)dir*Mn*Din;
    const unsigned short* W = dir ? xwb : xwf;
    float* C = xd + (size_t)dir*Mn*40;
    int tid = threadIdx.x;
    int wave = tid >> 6, lane = tid & 63;
    int quad = lane >> 4, fr = lane & 15;
    int arow = tid >> 2;
    int c8   = (tid & 3) << 3;
    int mg = m0 + arow; if (mg >= Mn) mg = Mn - 1;
    int wrow = arow < 40 ? arow : 39;
    f32x4 acc[4] = {};
    {
        bf16x8 a0 = *(const bf16x8*)(A + (size_t)mg*Din + c8);
        bf16x8 a1 = *(const bf16x8*)(A + (size_t)mg*Din + c8 + 32);
        bf16x8 w0 = *(const bf16x8*)(W + (size_t)wrow*Din + c8);
        bf16x8 w1 = *(const bf16x8*)(W + (size_t)wrow*Din + c8 + 32);
        *(bf16x8*)&As[0][arow][c8]      = a0;
        *(bf16x8*)&As[0][arow][c8 + 32] = a1;
        *(bf16x8*)&Bs[0][arow][c8]      = w0;
        *(bf16x8*)&Bs[0][arow][c8 + 32] = w1;
    }
    int cur = 0;
    for (int k0 = 64; k0 <= Din; k0 += 64) {
        bool more = (k0 < Din);
        bf16x8 a0, a1, w0, w1;
        if (more) {
            a0 = *(const bf16x8*)(A + (size_t)mg*Din + k0 + c8);
            a1 = *(const bf16x8*)(A + (size_t)mg*Din + k0 + c8 + 32);
            w0 = *(const bf16x8*)(W + (size_t)wrow*Din + k0 + c8);
            w1 = *(const bf16x8*)(W + (size_t)wrow*Din + k0 + c8 + 32);
        }
        __syncthreads();
        bf16x8 af0 = *(const bf16x8*)&As[cur][wave*16 + fr][quad << 3];
        bf16x8 af1 = *(const bf16x8*)&As[cur][wave*16 + fr][(quad << 3) + 32];
        #pragma unroll
        for (int nt = 0; nt < 4; ++nt) {
            bf16x8 b0 = *(const bf16x8*)&Bs[cur][nt*16 + fr][quad << 3];
            bf16x8 b1 = *(const bf16x8*)&Bs[cur][nt*16 + fr][(quad << 3) + 32];
            acc[nt] = __builtin_amdgcn_mfma_f32_16x16x32_bf16(af0, b0, acc[nt], 0, 0, 0);
            acc[nt] = __builtin_amdgcn_mfma_f32_16x16x32_bf16(af1, b1, acc[nt], 0, 0, 0);
        }
        if (more) {
            *(bf16x8*)&As[cur^1][arow][c8]      = a0;
            *(bf16x8*)&As[cur^1][arow][c8 + 32] = a1;
            *(bf16x8*)&Bs[cur^1][arow][c8]      = w0;
            *(bf16x8*)&Bs[cur^1][arow][c8 + 32] = w1;
            cur ^= 1;
        }
    }
    #pragma unroll
    for (int nt = 0; nt < 4; ++nt) {
        int col = nt*16 + fr;
        if (col >= 40) continue;
        #pragma unroll
        for (int r = 0; r < 4; ++r) {
            int mgo = m0 + wave*16 + quad*4 + r;
            if (mgo < Mn) C[(size_t)mgo*40 + col] = acc[nt][r];
        }
    }
}

__global__ __launch_bounds__(256) void scanA(
    const unsigned short* __restrict__ u, const float* __restrict__ xd,
    const float* __restrict__ dwf, const float* __restrict__ dbf,
    const float* __restrict__ dwb, const float* __restrict__ dbb,
    const float* __restrict__ Alf, const float* __restrict__ Alb,
    float* __restrict__ Hsum, float* __restrict__ dtsum, int ndir)
{
    int gid = blockIdx.x*blockDim.x + threadIdx.x;
    if (gid >= ndir*Bn*NC*Din) return;
    int dir = gid / (Bn*NC*Din);
    int rem = gid % (Bn*NC*Din);
    int d = rem % Din;
    int bc = rem / Din;
    int c = bc % NC, b = bc / NC;
    const float* A_log = dir ? Alb : Alf;
    const float* dw = dir ? dwb : dwf;
    const float* db = dir ? dbb : dbf;
    float A[Sn];
    #pragma unroll
    for (int s = 0; s < Sn; ++s) A[s] = -__expf(A_log[d*Sn + s]);
    float dwr[Rn];
    #pragma unroll
    for (int r = 0; r < Rn; ++r) dwr[r] = dw[d*Rn + r];
    float dbv = db[d];
    float hs[Sn] = {0,0,0,0,0,0,0,0};
    float sdt = 0.f;
    int l0 = c*CL;
    const unsigned short* up = u + (size_t)dir*Mn*Din + ((size_t)b*Ln + l0)*Din + d;
    const float* xp = xd + (size_t)dir*Mn*40 + ((size_t)b*Ln + l0)*40;
    #pragma unroll
    for (int l = 0; l < CL; ++l) {
        float uv = us2f(up[(size_t)l*Din]);
        const float* xr = xp + l*40;
        float dta = dbv;
        #pragma unroll
        for (int r = 0; r < Rn; ++r) dta = fmaf(xr[r], dwr[r], dta);
        float dtv = (dta > 20.f) ? dta : log1pf(__expf(dta));
        sdt += dtv;
        const float4* B4 = (const float4*)(xr + Rn);
        float4 Bv0 = B4[0], Bv1 = B4[1];
        float du = dtv * uv;
        hs[0] = fmaf(__expf(dtv*A[0]), hs[0], du*Bv0.x);
        hs[1] = fmaf(__expf(dtv*A[1]), hs[1], du*Bv0.y);
        hs[2] = fmaf(__expf(dtv*A[2]), hs[2], du*Bv0.z);
        hs[3] = fmaf(__expf(dtv*A[3]), hs[3], du*Bv0.w);
        hs[4] = fmaf(__expf(dtv*A[4]), hs[4], du*Bv1.x);
        hs[5] = fmaf(__expf(dtv*A[5]), hs[5], du*Bv1.y);
        hs[6] = fmaf(__expf(dtv*A[6]), hs[6], du*Bv1.z);
        hs[7] = fmaf(__expf(dtv*A[7]), hs[7], du*Bv1.w);
    }
    float4* Hp = (float4*)(Hsum + (size_t)gid*8);
    Hp[0] = make_float4(hs[0], hs[1], hs[2], hs[3]);
    Hp[1] = make_float4(hs[4], hs[5], hs[6], hs[7]);
    dtsum[gid] = sdt;
}

__global__ __launch_bounds__(256) void scanB(
    const float* __restrict__ Alf, const float* __restrict__ Alb,
    float* __restrict__ Hsum, const float* __restrict__ dtsum, int ndir)
{
    int gid = blockIdx.x*blockDim.x + threadIdx.x;
    if (gid >= ndir*Bn*Din*Sn) return;
    int s   = gid & 7;
    int rem = gid >> 3;
    int d   = rem % Din;
    int t   = rem / Din;
    int b   = t % Bn, dir = t / Bn;
    const float* A_log = dir ? Alb : Alf;
    float Av = -__expf(A_log[d*Sn + s]);
    float h = 0.f;
    size_t base = (size_t)dir*Bn*NC*Din + (size_t)b*NC*Din + d;
    float* Hp = Hsum + base*8 + s;
    const float* dp = dtsum + base;
    #pragma unroll 7
    for (int c = 0; c < NC; ++c) {
        size_t off = (size_t)c*Din;
        float H = Hp[off*8];
        float sdt = dp[off];
        Hp[off*8] = h;
        h = fmaf(__expf(Av*sdt), h, H);
    }
}

__global__ __launch_bounds__(256) void scanC(
    const unsigned short* __restrict__ u, const float* __restrict__ xd,
    const float* __restrict__ dwf, const float* __restrict__ dbf,
    const float* __restrict__ dwb, const float* __restrict__ dbb,
    const float* __restrict__ Alf, const float* __restrict__ Alb,
    const float* __restrict__ Dpf, const float* __restrict__ Dpb,
    const float* __restrict__ Hsum, unsigned short* __restrict__ yt, int ndir)
{
    int gid = blockIdx.x*blockDim.x + threadIdx.x;
    if (gid >= ndir*Bn*NC*Din) return;
    int dir = gid / (Bn*NC*Din);
    int rem = gid % (Bn*NC*Din);
    int d = rem % Din;
    int bc = rem / Din;
    int c = bc % NC, b = bc / NC;
    const float* A_log = dir ? Alb : Alf;
    const float* dw = dir ? dwb : dwf;
    const float* db = dir ? dbb : dbf;
    const float* Dp = dir ? Dpb : Dpf;
    float A[Sn];
    #pragma unroll
    for (int s = 0; s < Sn; ++s) A[s] = -__expf(A_log[d*Sn + s]);
    float dwr[Rn];
    #pragma unroll
    for (int r = 0; r < Rn; ++r) dwr[r] = dw[d*Rn + r];
    float dbv = db[d];
    const float4* hp = (const float4*)(Hsum + (size_t)gid*8);
    float4 h0 = hp[0], h1 = hp[1];
    float hs[Sn] = {h0.x, h0.y, h0.z, h0.w, h1.x, h1.y, h1.z, h1.w};
    float Dd = Dp[d];
    int l0 = c*CL;
    const unsigned short* up = u + (size_t)dir*Mn*Din + ((size_t)b*Ln + l0)*Din + d;
    const float* xp = xd + (size_t)dir*Mn*40 + ((size_t)b*Ln + l0)*40;
    unsigned short* yp = yt + (size_t)dir*Mn*Din + (size_t)b*Ln*Din + d;
    #pragma unroll
    for (int l = 0; l < CL; ++l) {
        int gl = l0 + l;
        float uv = us2f(up[(size_t)l*Din]);
        const float* xr = xp + l*40;
        float dta = dbv;
        #pragma unroll
        for (int r = 0; r < Rn; ++r) dta = fmaf(xr[r], dwr[r], dta);
        float dtv = (dta > 20.f) ? dta : log1pf(__expf(dta));
        const float4* B4 = (const float4*)(xr + Rn);
        float4 Bv0 = B4[0], Bv1 = B4[1], Cv0 = B4[2], Cv1 = B4[3];
        float du = dtv * uv;
        float yv = 0.f;
        hs[0] = fmaf(__expf(dtv*A[0]), hs[0], du*Bv0.x); yv = fmaf(hs[0], Cv0.x, yv);
        hs[1] = fmaf(__expf(dtv*A[1]), hs[1], du*Bv0.y); yv = fmaf(hs[1], Cv0.y, yv);
        hs[2] = fmaf(__expf(dtv*A[2]), hs[2], du*Bv0.z); yv = fmaf(hs[2], Cv0.z, yv);
        hs[3] = fmaf(__expf(dtv*A[3]), hs[3], du*Bv0.w); yv = fmaf(hs[3], Cv0.w, yv);
        hs[4] = fmaf(__expf(dtv*A[4]), hs[4], du*Bv1.x); yv = fmaf(hs[4], Cv1.x, yv);
        hs[5] = fmaf(__expf(dtv*A[5]), hs[5], du*Bv1.y); yv = fmaf(hs[5], Cv1.y, yv);
        hs[6] = fmaf(__expf(dtv*A[6]), hs[6], du*Bv1.z); yv = fmaf(hs[6], Cv1.z, yv);
        hs[7] = fmaf(__expf(dtv*A[7]), hs[7], du*Bv1.w); yv = fmaf(hs[7], Cv1.w, yv);
        yv = fmaf(uv, Dd, yv);
        int ol = dir ? (Ln - 1 - gl) : gl;
        yp[(size_t)ol*Din] = f2us(yv);
    }
}

// ------------------------- final rmsnorm (h + h2 + res), h2 = split-K partial
__global__ __launch_bounds__(256) void final_k(
    const float* __restrict__ h, const float* __restrict__ h2,
    const float* __restrict__ res, const float* __restrict__ w,
    float* __restrict__ out)
{
    int wid  = (blockIdx.x * blockDim.x + threadIdx.x) >> 6;
    int lane = threadIdx.x & 63;
    if (wid >= Mn) return;
    const float* hp = h + (size_t)wid*En;
    const float* h2p = h2 + (size_t)wid*En;
    const float* rp = res + (size_t)wid*En;
    float v[6]; float ss = 0.f;
    #pragma unroll
    for (int j = 0; j < 6; ++j) {
        int e = lane + j*64;
        float r = hp[e] + h2p[e] + rp[e];
        v[j] = r; ss = fmaf(r, r, ss);
    }
    #pragma unroll
    for (int off = 32; off; off >>= 1) ss += __shfl_xor(ss, off, 64);
    float scale = rsqrtf(ss * (1.f/(float)En) + 1e-5f);
    #pragma unroll
    for (int j = 0; j < 6; ++j) {
        int e = lane + j*64;
        out[(size_t)wid*En + e] = v[j] * scale * w[e];
    }
}

extern "C" void kernel_launch(void* const* d_in, const int* in_sizes, int n_in,
                              void* d_out, int out_size, void* d_ws, size_t ws_size,
                              hipStream_t stream)
{
    const float* x         = (const float*)d_in[0];
    const float* patch_w   = (const float*)d_in[1];
    const float* patch_b   = (const float*)d_in[2];
    const float* pos_embed = (const float*)d_in[3];
    const float* in_proj_w = (const float*)d_in[4];
    const float* conv_w    = (const float*)d_in[5];
    const float* conv_b    = (const float*)d_in[6];
    const float* xproj_w   = (const float*)d_in[7];
    const float* dtproj_w  = (const float*)d_in[8];
    const float* dtproj_b  = (const float*)d_in[9];
    const float* A_log     = (const float*)d_in[10];
    const float* D_param   = (const float*)d_in[11];
    const float* outproj_w = (const float*)d_in[12];
    const float* norm_w    = (const float*)d_in[13];
    const float* conv_wb   = (const float*)d_in[14];
    const float* conv_bb   = (const float*)d_in[15];
    const float* xproj_wb  = (const float*)d_in[16];
    const float* dtproj_wb = (const float*)d_in[17];
    const float* dtproj_bb = (const float*)d_in[18];
    const float* A_log_b   = (const float*)d_in[19];
    const float* D_b       = (const float*)d_in[20];
    const float* norm_f_w  = (const float*)d_in[21];

    // ---- carve (~56 MB; ws ~268 MB per fillBuffer WRITE_SIZE evidence)
    float* pf   = (float*)d_ws;
    float* h    = pf;  pf += (size_t)Mn*En;
    float* h2   = pf;  pf += (size_t)Mn*En;            // split-K partial (z=1)
    float* res  = pf;  pf += (size_t)Mn*En;
    float* xd   = pf;  pf += (size_t)2*Mn*40;          // [dir][m][40]
    float* Hsum = pf;  pf += (size_t)2*Bn*NC*Din*Sn;   // [dir][b][c][d][8]
    float* dtsm = pf;  pf += (size_t)2*Bn*NC*Din;
    unsigned short* ub = (unsigned short*)pf;
    unsigned short* xz = ub;  ub += (size_t)Mn*1536;
    unsigned short* u  = ub;  ub += (size_t)2*Mn*Din;   // [dir][m][d]; hn overlays
    unsigned short* hn = u;
    unsigned short* yt = ub;  ub += (size_t)2*Mn*Din;   // [dir][m][d]
    unsigned short* w_in = ub;  ub += (size_t)NW0;      // bf16 weights
    unsigned short* w_out= ub;  ub += (size_t)NW1;
    unsigned short* w_xf = ub;  ub += (size_t)NW2;
    unsigned short* w_xb = ub;  ub += (size_t)NW3;
    unsigned short* w_pm = ub;  ub += (size_t)NW4;
    unsigned short* pm = (unsigned short*)Hsum;         // overlay: pre-loop only
    size_t needed = (size_t)((char*)ub - (char*)d_ws);
    if (ws_size < needed) return;

    const int wave_blocks = (Mn*64)/256;             // 392
    const int B_me   = (Mn*En + 255)/256;
    const int B_md   = (Mn*768 + 255)/256;           // 4704
    const int B_cw   = ((NW0+NW1+NW2+NW3+NW4)/4 + 255)/256;
    const int mTiles = (Mn + 63)/64;                 // 25

    // ---- coop grid sized to occupancy (deadlock-proof; query once)
    static int coop_grid = -1;
    if (coop_grid < 0) {
        int mb = 0;
        hipError_t qe = hipOccupancyMaxActiveBlocksPerMultiprocessor(
            &mb, reinterpret_cast<const void*>(coop_scan), 256, 0);
        int cap = (qe == hipSuccess && mb > 0) ? mb * 256 : 512;
        coop_grid = cap < 768 ? cap : 768;
        if (coop_grid < 8) coop_grid = 8;
    }

    // ---- weight pre-cast + patch embed (patch GEMM split-K x2: h, h2)
    k_castw<<<B_cw, 256, 0, stream>>>(in_proj_w, outproj_w, xproj_w, xproj_wb,
                                      patch_w, w_in, w_out, w_xf, w_xb, w_pm);
    k_patch<<<B_md, 256, 0, stream>>>(x, pm);
    dim3 g0((En/64)*2, mTiles);
    gemm_mfma<float,0,2><<<g0, 256, 0, stream>>>(pm, nullptr, nullptr, w_pm,
                                                 h, En, Mn, En, 768, 1);
    k_posadd<<<B_me, 256, 0, stream>>>(h, h2, patch_b, pos_embed);

    for (int i = 0; i < DEPTH; ++i) {
        int ndir = (i < NSPA) ? 2 : 1;
        rms_residual<<<wave_blocks, 256, 0, stream>>>(h, h2, res, hn,
                                                      norm_w + (size_t)i*En, i == 0);

        dim3 g1(1536/64, mTiles);
        gemm_mfma<unsigned short,0,1><<<g1, 256, 0, stream>>>(
            hn, nullptr, nullptr, w_in + (size_t)i*1536*En,
            xz, 1536, Mn, 1536, En, 1);

        const float* cwf = conv_w + (size_t)i*Din*4;
        const float* cbf = conv_b + (size_t)i*Din;
        const float* dwf = dtproj_w + (size_t)i*Din*Rn;
        const float* dbf = dtproj_b + (size_t)i*Din;
        const float* Alf = A_log + (size_t)i*Din*Sn;
        const float* Dpf = D_param + (size_t)i*Din;
        const float* cwb = conv_wb + (size_t)i*Din*4;
        const float* cbb = conv_bb + (size_t)i*Din;
        const float* dwb = dtproj_wb + (size_t)i*Din*Rn;
        const float* dbb = dtproj_bb + (size_t)i*Din;
        const float* Alb = A_log_b + (size_t)i*Din*Sn;
        const float* Dpb = D_b + (size_t)i*Din;
        const unsigned short* xwf = w_xf + (size_t)i*40*Din;
        const unsigned short* xwb = w_xb + (size_t)i*40*Din;

        CoopP cp;
        cp.xz = xz; cp.cwf = cwf; cp.cbf = cbf; cp.cwb = cwb; cp.cbb = cbb;
        cp.xwf = xwf; cp.xwb = xwb; cp.u = u; cp.xd = xd;
        cp.dwf = dwf; cp.dbf = dbf; cp.dwb = dwb; cp.dbb = dbb;
        cp.Alf = Alf; cp.Alb = Alb; cp.Dpf = Dpf; cp.Dpb = Dpb;
        cp.Hsum = Hsum; cp.dtsum = dtsm; cp.yt = yt; cp.ndir = ndir;
        void* cargs[] = { &cp };
        hipError_t cerr = hipLaunchCooperativeKernel(
            (const void*)coop_scan, dim3(coop_grid), dim3(256), cargs, 0, stream);
        if (cerr != hipSuccess) {
            // legacy 5-kernel fallback (bit-identical math)
            int c_blocks  = (ndir*Mn*Din + 255)/256;
            int sA_blocks = (ndir*Bn*NC*Din + 255)/256;
            int sB_blocks = (ndir*Bn*Din*Sn + 255)/256;
            k_conv2<<<c_blocks, 256, 0, stream>>>(xz, cwf, cbf, cwb, cbb, u, ndir);
            dim3 gx(ndir, mTiles);
            xproj_gemm<<<gx, 256, 0, stream>>>(u, xwf, xwb, xd);
            scanA<<<sA_blocks, 256, 0, stream>>>(u, xd, dwf, dbf, dwb, dbb,
                                                 Alf, Alb, Hsum, dtsm, ndir);
            scanB<<<sB_blocks, 256, 0, stream>>>(Alf, Alb, Hsum, dtsm, ndir);
            scanC<<<sA_blocks, 256, 0, stream>>>(u, xd, dwf, dbf, dwb, dbb,
                                                 Alf, Alb, Dpf, Dpb, Hsum, yt, ndir);
        }

        dim3 g2((En/64)*2, mTiles);
        gemm_mfma<float,1,2><<<g2, 256, 0, stream>>>(
            yt, yt + (size_t)Mn*Din, xz + Din, w_out + (size_t)i*En*Din,
            h, En, Mn, En, Din, ndir);
    }

    final_k<<<wave_blocks, 256, 0, stream>>>(h, h2, res, norm_f_w, (float*)d_out);
}

// Round 11
// 1198.570 us; speedup vs baseline: 4.6749x; 2.7395x over previous
//
#include <hip/hip_runtime.h>
#include <hip/hip_bf16.h>
#include <math.h>

// EndoMamba r24 = r20b exactly (best verified: 1199.5 us).
// Coop-fusion branch (r21-r23) abandoned: even spill-free (r23, VGPR 80) the
// fused kernel runs 430us vs ~65us for the 5 legacy launches — residency-
// limited grid (2 blocks/CU) strangles the latency-bound streaming phases,
// and grid.sync device-fences across 8 non-coherent XCD L2s each phase.
// Kernel-boundary overhead (~1-2us) is cheaper than grid-wide sync here.
// State: split-K x2 out_proj/patch GEMMs (partial add folded into
// rms_residual/k_posadd/final_k); bf16 pre-cast weights; BK=64 dbuf GEMM;
// bijective XCD swizzle; streaming conv; xproj as MFMA GEMM; 3-phase scan.
#define Bn   2
#define Tn   4
#define Nn   196
#define Ln   784
#define Mn   1568
#define En   384
#define Din  768
#define Sn   8
#define Rn   24
#define DEPTH 12
#define NSPA 6
#define NC   98
#define CL   8      // 784 = 98*8

typedef __attribute__((ext_vector_type(8))) short bf16x8;
typedef __attribute__((ext_vector_type(4))) float f32x4;

__device__ __forceinline__ float siluf(float v) { return v / (1.f + __expf(-v)); }
__device__ __forceinline__ float us2f(unsigned short u) {
    union { unsigned int i; float f; } v; v.i = (unsigned)u << 16; return v.f;
}
__device__ __forceinline__ unsigned short f2us(float f) {
    __hip_bfloat16 b = __float2bfloat16(f);
    return *(unsigned short*)&b;
}
__device__ __forceinline__ void cstore(float* p, float v) { *p = v; }
__device__ __forceinline__ void cstore(unsigned short* p, float v) { *p = f2us(v); }

// bijective XCD swizzle (m204): consecutive flats within an XCD share n-tile
__device__ __forceinline__ void xcd_tile(int ny, int& n0, int& m0)
{
    int nx = gridDim.x;
    int total = nx*ny;
    int bid = blockIdx.y*nx + blockIdx.x;
    int q = total >> 3, r = total & 7;
    int xcd = bid & 7, idx = bid >> 3;
    int base = (xcd < r) ? xcd*(q+1) : r*(q+1) + (xcd - r)*q;
    int flat = base + idx;
    n0 = (flat / ny) * 64;
    m0 = (flat % ny) * 64;
}

// -------------------- weight pre-cast fp32 -> bf16 (once per launch)
#define NW0 7077888   // in_proj 12*1536*384
#define NW1 3538944   // outproj 12*384*768
#define NW2 368640    // xproj fwd 12*40*768
#define NW3 184320    // xproj bwd 6*40*768
#define NW4 294912    // patch 384*768
__device__ __forceinline__ void cast4(unsigned short* d, const float* s)
{
    float4 v = *(const float4*)s;
    ushort4 o;
    o.x = f2us(v.x); o.y = f2us(v.y); o.z = f2us(v.z); o.w = f2us(v.w);
    *(ushort4*)d = o;
}
__global__ __launch_bounds__(256) void k_castw(
    const float* __restrict__ w0, const float* __restrict__ w1,
    const float* __restrict__ w2, const float* __restrict__ w3,
    const float* __restrict__ w4,
    unsigned short* __restrict__ o0, unsigned short* __restrict__ o1,
    unsigned short* __restrict__ o2, unsigned short* __restrict__ o3,
    unsigned short* __restrict__ o4)
{
    int i4 = (blockIdx.x*blockDim.x + threadIdx.x)*4;
    if (i4 < NW0) { cast4(o0+i4, w0+i4); return; }
    i4 -= NW0;
    if (i4 < NW1) { cast4(o1+i4, w1+i4); return; }
    i4 -= NW1;
    if (i4 < NW2) { cast4(o2+i4, w2+i4); return; }
    i4 -= NW2;
    if (i4 < NW3) { cast4(o3+i4, w3+i4); return; }
    i4 -= NW3;
    if (i4 < NW4) { cast4(o4+i4, w4+i4); }
}

// ------------------------------------------- patch gather -> pm[m,768] bf16
__global__ __launch_bounds__(256) void k_patch(
    const float* __restrict__ x, unsigned short* __restrict__ pm)
{
    int gid = blockIdx.x*blockDim.x + threadIdx.x;
    if (gid >= Mn*768) return;
    int idx = gid % 768, token = gid / 768;
    int b = token / Ln, l = token % Ln;
    int t = l / Nn, n = l % Nn;
    int hh = n / 14, ww = n % 14;
    int c = idx >> 8, rem = idx & 255, p = rem >> 4, q = rem & 15;
    pm[gid] = f2us(x[(((size_t)(b*3 + c)*Tn + t)*224 + (hh*16 + p))*224 + (ww*16 + q)]);
}

// ---------------- embed epilogue: h = h + h2 + pb + pos + pe (split-K add)
__global__ __launch_bounds__(256) void k_posadd(
    float* __restrict__ h, const float* __restrict__ h2,
    const float* __restrict__ pb, const float* __restrict__ pos)
{
    int gid = blockIdx.x*blockDim.x + threadIdx.x;
    if (gid >= Mn*En) return;
    int e = gid % En, token = gid / En;
    int l = token % Ln;
    int t = l / Nn, n = l % Nn;
    float div = __expf(-logf(10000.f) * (float)(e & ~1) / (float)En);
    float ang = (float)t * div;
    h[gid] += h2[gid] + pb[e] + pos[n*En + e] + ((e & 1) ? cosf(ang) : sinf(ang));
}

// -------------------- rmsnorm (+ residual); h2 = split-K partial of out_proj
__global__ __launch_bounds__(256) void rms_residual(
    const float* __restrict__ hin, const float* __restrict__ h2,
    float* __restrict__ res, unsigned short* __restrict__ hn,
    const float* __restrict__ w, int first)
{
    int wid  = (blockIdx.x * blockDim.x + threadIdx.x) >> 6;   // token
    int lane = threadIdx.x & 63;
    if (wid >= Mn) return;
    const float* hp = hin + (size_t)wid*En;
    const float* h2p = h2 + (size_t)wid*En;
    float* rp = res + (size_t)wid*En;
    float v[6]; float ss = 0.f;
    #pragma unroll
    for (int j = 0; j < 6; ++j) {
        int e = lane + j*64;
        float r = first ? hp[e] : (hp[e] + h2p[e] + rp[e]);
        v[j] = r; ss = fmaf(r, r, ss);
    }
    #pragma unroll
    for (int off = 32; off; off >>= 1) ss += __shfl_xor(ss, off, 64);
    float scale = rsqrtf(ss * (1.f/(float)En) + 1e-5f);
    #pragma unroll
    for (int j = 0; j < 6; ++j) {
        int e = lane + j*64;
        rp[e] = v[j];
        hn[(size_t)wid*En + e] = f2us(v[j] * scale * w[e]);
    }
}

// ---------------- bf16 MFMA GEMM: C = A[M,K] * Wb[N,K]^T, Wb bf16 (pre-cast)
// BK=64 double-buffered, one barrier per step, XCD-swizzled tiles.
// SK: split-K factor; z-th partial written to C + z*M*ldc.
// GATED: A_eff = (yf + (ndir==2? yb:0)) * silu(z), all bf16 inputs.
template<typename CT, int GATED, int SK>
__global__ __launch_bounds__(256) void gemm_mfma(
    const unsigned short* __restrict__ A,     // bf16 A (or yf when GATED)
    const unsigned short* __restrict__ Yb,    // yb (GATED only)
    const unsigned short* __restrict__ Z,     // z base, row stride 1536 (GATED)
    const unsigned short* __restrict__ Wb,    // bf16 W [N][K]
    CT* __restrict__ C, int ldc, int M, int N, int K, int ndir)
{
    __shared__ unsigned short As[2][64][72];   // 64 k + 8 pad
    __shared__ unsigned short Bs[2][64][72];
    int n0, m0;
    xcd_tile((M + 63) >> 6, n0, m0);
    int nidx = n0 >> 6;
    int zk = nidx % SK;
    n0 = (nidx / SK) * 64;
    int kbeg = zk * (K / SK);
    int kend = kbeg + K / SK;
    CT* Cz = C + (size_t)zk*M*ldc;
    int tid = threadIdx.x;
    int wave = tid >> 6, lane = tid & 63;
    int quad = lane >> 4, fr = lane & 15;
    int arow = tid >> 2;            // 0..63
    int c8   = (tid & 3) << 3;      // 0,8,16,24
    int mg = m0 + arow; if (mg >= M) mg = M - 1;
    f32x4 acc[4] = {};

    auto gate8 = [&](const unsigned short* yf, const unsigned short* yb,
                     const unsigned short* zp) -> bf16x8 {
        bf16x8 f = *(const bf16x8*)yf;
        bf16x8 bb = *(const bf16x8*)yb;
        bf16x8 zz = *(const bf16x8*)zp;
        unsigned short o[8];
        const unsigned short* fu = (const unsigned short*)&f;
        const unsigned short* bu = (const unsigned short*)&bb;
        const unsigned short* zu = (const unsigned short*)&zz;
        #pragma unroll
        for (int j = 0; j < 8; ++j) {
            float v = us2f(fu[j]);
            if (ndir == 2) v += us2f(bu[j]);
            o[j] = f2us(v * siluf(us2f(zu[j])));
        }
        return *(bf16x8*)o;
    };

    auto load_tile = [&](int k0, bf16x8& av0, bf16x8& av1,
                         bf16x8& wv0, bf16x8& wv1) {
        if (!GATED) {
            av0 = *(const bf16x8*)(A + (size_t)mg*K + k0 + c8);
            av1 = *(const bf16x8*)(A + (size_t)mg*K + k0 + c8 + 32);
        } else {
            size_t ro = (size_t)mg*K + k0 + c8;
            size_t zo = (size_t)mg*1536 + k0 + c8;
            av0 = gate8(A + ro, Yb + ro, Z + zo);
            av1 = gate8(A + ro + 32, Yb + ro + 32, Z + zo + 32);
        }
        wv0 = *(const bf16x8*)(Wb + (size_t)(n0 + arow)*K + k0 + c8);
        wv1 = *(const bf16x8*)(Wb + (size_t)(n0 + arow)*K + k0 + c8 + 32);
    };

    {   // prologue: stage first k-tile into buffer 0
        bf16x8 a0, a1, w0, w1;
        load_tile(kbeg, a0, a1, w0, w1);
        *(bf16x8*)&As[0][arow][c8]      = a0;
        *(bf16x8*)&As[0][arow][c8 + 32] = a1;
        *(bf16x8*)&Bs[0][arow][c8]      = w0;
        *(bf16x8*)&Bs[0][arow][c8 + 32] = w1;
    }
    int cur = 0;
    for (int k0 = kbeg + 64; k0 <= kend; k0 += 64) {
        bool more = (k0 < kend);
        bf16x8 a0, a1, w0, w1;
        if (more) load_tile(k0, a0, a1, w0, w1);   // issue loads before barrier
        __syncthreads();
        bf16x8 af0 = *(const bf16x8*)&As[cur][wave*16 + fr][quad << 3];
        bf16x8 af1 = *(const bf16x8*)&As[cur][wave*16 + fr][(quad << 3) + 32];
        #pragma unroll
        for (int nt = 0; nt < 4; ++nt) {
            bf16x8 b0 = *(const bf16x8*)&Bs[cur][nt*16 + fr][quad << 3];
            bf16x8 b1 = *(const bf16x8*)&Bs[cur][nt*16 + fr][(quad << 3) + 32];
            acc[nt] = __builtin_amdgcn_mfma_f32_16x16x32_bf16(af0, b0, acc[nt], 0, 0, 0);
            acc[nt] = __builtin_amdgcn_mfma_f32_16x16x32_bf16(af1, b1, acc[nt], 0, 0, 0);
        }
        if (more) {
            *(bf16x8*)&As[cur^1][arow][c8]      = a0;
            *(bf16x8*)&As[cur^1][arow][c8 + 32] = a1;
            *(bf16x8*)&Bs[cur^1][arow][c8]      = w0;
            *(bf16x8*)&Bs[cur^1][arow][c8 + 32] = w1;
            cur ^= 1;
        }
    }
    #pragma unroll
    for (int nt = 0; nt < 4; ++nt) {
        #pragma unroll
        for (int r = 0; r < 4; ++r) {
            int mgo = m0 + wave*16 + quad*4 + r;
            if (mgo < M) cstore(Cz + (size_t)mgo*ldc + n0 + nt*16 + fr, acc[nt][r]);
        }
    }
}

// ------ u = silu(conv(xz)) both dirs in one launch: u[dir][m][d] bf16
// (streaming, full-grid parallelism — 9408 blocks; do NOT fuse into xproj)
__global__ __launch_bounds__(256) void k_conv2(
    const unsigned short* __restrict__ xz,
    const float* __restrict__ cwf, const float* __restrict__ cbf,
    const float* __restrict__ cwb, const float* __restrict__ cbb,
    unsigned short* __restrict__ u, int ndir)
{
    int gid = blockIdx.x*blockDim.x + threadIdx.x;
    if (gid >= ndir*Mn*Din) return;
    int dir = gid / (Mn*Din);
    int rem = gid % (Mn*Din);
    int d = rem % Din, m = rem / Din;
    int l = m % Ln, b = m / Ln;
    const float* cw = dir ? cwb : cwf;
    const float* cb = dir ? cbb : cbf;
    float4 cwv = *(const float4*)(cw + d*4);
    float acc = cb[d];
    #pragma unroll
    for (int k = 0; k < 4; ++k) {
        int ls = l - 3 + k;
        if (ls < 0) continue;
        int lsrc = dir ? (Ln - 1 - ls) : ls;
        float cwk = (k==0)?cwv.x:(k==1)?cwv.y:(k==2)?cwv.z:cwv.w;
        acc = fmaf(us2f(xz[(size_t)(b*Ln + lsrc)*1536 + d]), cwk, acc);
    }
    u[gid] = f2us(siluf(acc));
}

// ------ xproj as MFMA GEMM: xd[dir][m][40] = u[dir][m][768] * xw[40][768]^T
// BK=64, one 64-wide N-tile (W rows 40..63 clamped, cols >=40 not stored).
// grid = (ndir, 25), swizzled; W bf16 pre-cast, selected per dir.
__global__ __launch_bounds__(256) void xproj_gemm(
    const unsigned short* __restrict__ u,
    const unsigned short* __restrict__ xwf, const unsigned short* __restrict__ xwb,
    float* __restrict__ xd)
{
    __shared__ unsigned short As[2][64][72];
    __shared__ unsigned short Bs[2][64][72];
    int n0d, m0;
    xcd_tile((Mn + 63) >> 6, n0d, m0);
    int dir = n0d >> 6;                       // n-tile index == dir
    const unsigned short* A = u + (size_t)dir*Mn*Din;
    const unsigned short* W = dir ? xwb : xwf;
    float* C = xd + (size_t)dir*Mn*40;
    int tid = threadIdx.x;
    int wave = tid >> 6, lane = tid & 63;
    int quad = lane >> 4, fr = lane & 15;
    int arow = tid >> 2;
    int c8   = (tid & 3) << 3;
    int mg = m0 + arow; if (mg >= Mn) mg = Mn - 1;
    int wrow = arow < 40 ? arow : 39;
    f32x4 acc[4] = {};

    auto load_tile = [&](int k0, bf16x8& av0, bf16x8& av1,
                         bf16x8& wv0, bf16x8& wv1) {
        av0 = *(const bf16x8*)(A + (size_t)mg*Din + k0 + c8);
        av1 = *(const bf16x8*)(A + (size_t)mg*Din + k0 + c8 + 32);
        wv0 = *(const bf16x8*)(W + (size_t)wrow*Din + k0 + c8);
        wv1 = *(const bf16x8*)(W + (size_t)wrow*Din + k0 + c8 + 32);
    };

    {
        bf16x8 a0, a1, w0, w1;
        load_tile(0, a0, a1, w0, w1);
        *(bf16x8*)&As[0][arow][c8]      = a0;
        *(bf16x8*)&As[0][arow][c8 + 32] = a1;
        *(bf16x8*)&Bs[0][arow][c8]      = w0;
        *(bf16x8*)&Bs[0][arow][c8 + 32] = w1;
    }
    int cur = 0;
    for (int k0 = 64; k0 <= Din; k0 += 64) {
        bool more = (k0 < Din);
        bf16x8 a0, a1, w0, w1;
        if (more) load_tile(k0, a0, a1, w0, w1);
        __syncthreads();
        bf16x8 af0 = *(const bf16x8*)&As[cur][wave*16 + fr][quad << 3];
        bf16x8 af1 = *(const bf16x8*)&As[cur][wave*16 + fr][(quad << 3) + 32];
        #pragma unroll
        for (int nt = 0; nt < 4; ++nt) {
            bf16x8 b0 = *(const bf16x8*)&Bs[cur][nt*16 + fr][quad << 3];
            bf16x8 b1 = *(const bf16x8*)&Bs[cur][nt*16 + fr][(quad << 3) + 32];
            acc[nt] = __builtin_amdgcn_mfma_f32_16x16x32_bf16(af0, b0, acc[nt], 0, 0, 0);
            acc[nt] = __builtin_amdgcn_mfma_f32_16x16x32_bf16(af1, b1, acc[nt], 0, 0, 0);
        }
        if (more) {
            *(bf16x8*)&As[cur^1][arow][c8]      = a0;
            *(bf16x8*)&As[cur^1][arow][c8 + 32] = a1;
            *(bf16x8*)&Bs[cur^1][arow][c8]      = w0;
            *(bf16x8*)&Bs[cur^1][arow][c8 + 32] = w1;
            cur ^= 1;
        }
    }
    #pragma unroll
    for (int nt = 0; nt < 4; ++nt) {
        int col = nt*16 + fr;
        if (col >= 40) continue;
        #pragma unroll
        for (int r = 0; r < 4; ++r) {
            int mgo = m0 + wave*16 + quad*4 + r;
            if (mgo < Mn) C[(size_t)mgo*40 + col] = acc[nt][r];
        }
    }
}

// ---------------- scan phase A: per-chunk (Sdt, H[8]); dt inline; both dirs
__global__ __launch_bounds__(256) void scanA(
    const unsigned short* __restrict__ u, const float* __restrict__ xd,
    const float* __restrict__ dwf, const float* __restrict__ dbf,
    const float* __restrict__ dwb, const float* __restrict__ dbb,
    const float* __restrict__ Alf, const float* __restrict__ Alb,
    float* __restrict__ Hsum, float* __restrict__ dtsum, int ndir)
{
    int gid = blockIdx.x*blockDim.x + threadIdx.x;
    if (gid >= ndir*Bn*NC*Din) return;
    int dir = gid / (Bn*NC*Din);
    int rem = gid % (Bn*NC*Din);
    int d = rem % Din;
    int bc = rem / Din;
    int c = bc % NC, b = bc / NC;
    const float* A_log = dir ? Alb : Alf;
    const float* dw = dir ? dwb : dwf;
    const float* db = dir ? dbb : dbf;
    float A[Sn];
    #pragma unroll
    for (int s = 0; s < Sn; ++s) A[s] = -__expf(A_log[d*Sn + s]);
    float dwr[Rn];
    #pragma unroll
    for (int r = 0; r < Rn; ++r) dwr[r] = dw[d*Rn + r];
    float dbv = db[d];
    float hs[Sn] = {0,0,0,0,0,0,0,0};
    float sdt = 0.f;
    int l0 = c*CL;
    const unsigned short* up = u + (size_t)dir*Mn*Din + ((size_t)b*Ln + l0)*Din + d;
    const float* xp = xd + (size_t)dir*Mn*40 + ((size_t)b*Ln + l0)*40;
    #pragma unroll
    for (int l = 0; l < CL; ++l) {
        float uv = us2f(up[(size_t)l*Din]);
        const float* xr = xp + l*40;
        float dta = dbv;
        #pragma unroll
        for (int r = 0; r < Rn; ++r) dta = fmaf(xr[r], dwr[r], dta);
        float dtv = (dta > 20.f) ? dta : log1pf(__expf(dta));
        sdt += dtv;
        const float4* B4 = (const float4*)(xr + Rn);
        float4 Bv0 = B4[0], Bv1 = B4[1];
        float du = dtv * uv;
        hs[0] = fmaf(__expf(dtv*A[0]), hs[0], du*Bv0.x);
        hs[1] = fmaf(__expf(dtv*A[1]), hs[1], du*Bv0.y);
        hs[2] = fmaf(__expf(dtv*A[2]), hs[2], du*Bv0.z);
        hs[3] = fmaf(__expf(dtv*A[3]), hs[3], du*Bv0.w);
        hs[4] = fmaf(__expf(dtv*A[4]), hs[4], du*Bv1.x);
        hs[5] = fmaf(__expf(dtv*A[5]), hs[5], du*Bv1.y);
        hs[6] = fmaf(__expf(dtv*A[6]), hs[6], du*Bv1.z);
        hs[7] = fmaf(__expf(dtv*A[7]), hs[7], du*Bv1.w);
    }
    float4* Hp = (float4*)(Hsum + (size_t)gid*8);
    Hp[0] = make_float4(hs[0], hs[1], hs[2], hs[3]);
    Hp[1] = make_float4(hs[4], hs[5], hs[6], hs[7]);
    dtsum[gid] = sdt;
}

// ---------------- scan phase B: serial fixup IN-PLACE on Hsum, both dirs.
__global__ __launch_bounds__(256) void scanB(
    const float* __restrict__ Alf, const float* __restrict__ Alb,
    float* __restrict__ Hsum, const float* __restrict__ dtsum, int ndir)
{
    int gid = blockIdx.x*blockDim.x + threadIdx.x;
    if (gid >= ndir*Bn*Din*Sn) return;
    int s   = gid & 7;
    int rem = gid >> 3;               // (dir*Bn + b)*Din + d
    int d   = rem % Din;
    int t   = rem / Din;
    int b   = t % Bn, dir = t / Bn;
    const float* A_log = dir ? Alb : Alf;
    float Av = -__expf(A_log[d*Sn + s]);
    float h = 0.f;
    size_t base = (size_t)dir*Bn*NC*Din + (size_t)b*NC*Din + d;
    float* Hp = Hsum + base*8 + s;
    const float* dp = dtsum + base;
    #pragma unroll 7
    for (int c = 0; c < NC; ++c) {
        size_t off = (size_t)c*Din;
        float H = Hp[off*8];
        float sdt = dp[off];
        Hp[off*8] = h;
        h = fmaf(__expf(Av*sdt), h, H);
    }
}

// -------- scan phase C: seeded local scan, raw y emit (no gate), both dirs
__global__ __launch_bounds__(256) void scanC(
    const unsigned short* __restrict__ u, const float* __restrict__ xd,
    const float* __restrict__ dwf, const float* __restrict__ dbf,
    const float* __restrict__ dwb, const float* __restrict__ dbb,
    const float* __restrict__ Alf, const float* __restrict__ Alb,
    const float* __restrict__ Dpf, const float* __restrict__ Dpb,
    const float* __restrict__ Hsum, unsigned short* __restrict__ yt, int ndir)
{
    int gid = blockIdx.x*blockDim.x + threadIdx.x;
    if (gid >= ndir*Bn*NC*Din) return;
    int dir = gid / (Bn*NC*Din);
    int rem = gid % (Bn*NC*Din);
    int d = rem % Din;
    int bc = rem / Din;
    int c = bc % NC, b = bc / NC;
    const float* A_log = dir ? Alb : Alf;
    const float* dw = dir ? dwb : dwf;
    const float* db = dir ? dbb : dbf;
    const float* Dp = dir ? Dpb : Dpf;
    float A[Sn];
    #pragma unroll
    for (int s = 0; s < Sn; ++s) A[s] = -__expf(A_log[d*Sn + s]);
    float dwr[Rn];
    #pragma unroll
    for (int r = 0; r < Rn; ++r) dwr[r] = dw[d*Rn + r];
    float dbv = db[d];
    const float4* hp = (const float4*)(Hsum + (size_t)gid*8);
    float4 h0 = hp[0], h1 = hp[1];
    float hs[Sn] = {h0.x, h0.y, h0.z, h0.w, h1.x, h1.y, h1.z, h1.w};
    float Dd = Dp[d];
    int l0 = c*CL;
    const unsigned short* up = u + (size_t)dir*Mn*Din + ((size_t)b*Ln + l0)*Din + d;
    const float* xp = xd + (size_t)dir*Mn*40 + ((size_t)b*Ln + l0)*40;
    unsigned short* yp = yt + (size_t)dir*Mn*Din + (size_t)b*Ln*Din + d;
    #pragma unroll
    for (int l = 0; l < CL; ++l) {
        int gl = l0 + l;
        float uv = us2f(up[(size_t)l*Din]);
        const float* xr = xp + l*40;
        float dta = dbv;
        #pragma unroll
        for (int r = 0; r < Rn; ++r) dta = fmaf(xr[r], dwr[r], dta);
        float dtv = (dta > 20.f) ? dta : log1pf(__expf(dta));
        const float4* B4 = (const float4*)(xr + Rn);
        float4 Bv0 = B4[0], Bv1 = B4[1], Cv0 = B4[2], Cv1 = B4[3];
        float du = dtv * uv;
        float yv = 0.f;
        hs[0] = fmaf(__expf(dtv*A[0]), hs[0], du*Bv0.x); yv = fmaf(hs[0], Cv0.x, yv);
        hs[1] = fmaf(__expf(dtv*A[1]), hs[1], du*Bv0.y); yv = fmaf(hs[1], Cv0.y, yv);
        hs[2] = fmaf(__expf(dtv*A[2]), hs[2], du*Bv0.z); yv = fmaf(hs[2], Cv0.z, yv);
        hs[3] = fmaf(__expf(dtv*A[3]), hs[3], du*Bv0.w); yv = fmaf(hs[3], Cv0.w, yv);
        hs[4] = fmaf(__expf(dtv*A[4]), hs[4], du*Bv1.x); yv = fmaf(hs[4], Cv1.x, yv);
        hs[5] = fmaf(__expf(dtv*A[5]), hs[5], du*Bv1.y); yv = fmaf(hs[5], Cv1.y, yv);
        hs[6] = fmaf(__expf(dtv*A[6]), hs[6], du*Bv1.z); yv = fmaf(hs[6], Cv1.z, yv);
        hs[7] = fmaf(__expf(dtv*A[7]), hs[7], du*Bv1.w); yv = fmaf(hs[7], Cv1.w, yv);
        yv = fmaf(uv, Dd, yv);
        int ol = dir ? (Ln - 1 - gl) : gl;
        yp[(size_t)ol*Din] = f2us(yv);
    }
}

// ------------------------- final rmsnorm (h + h2 + res), h2 = split-K partial
__global__ __launch_bounds__(256) void final_k(
    const float* __restrict__ h, const float* __restrict__ h2,
    const float* __restrict__ res, const float* __restrict__ w,
    float* __restrict__ out)
{
    int wid  = (blockIdx.x * blockDim.x + threadIdx.x) >> 6;
    int lane = threadIdx.x & 63;
    if (wid >= Mn) return;
    const float* hp = h + (size_t)wid*En;
    const float* h2p = h2 + (size_t)wid*En;
    const float* rp = res + (size_t)wid*En;
    float v[6]; float ss = 0.f;
    #pragma unroll
    for (int j = 0; j < 6; ++j) {
        int e = lane + j*64;
        float r = hp[e] + h2p[e] + rp[e];
        v[j] = r; ss = fmaf(r, r, ss);
    }
    #pragma unroll
    for (int off = 32; off; off >>= 1) ss += __shfl_xor(ss, off, 64);
    float scale = rsqrtf(ss * (1.f/(float)En) + 1e-5f);
    #pragma unroll
    for (int j = 0; j < 6; ++j) {
        int e = lane + j*64;
        out[(size_t)wid*En + e] = v[j] * scale * w[e];
    }
}

extern "C" void kernel_launch(void* const* d_in, const int* in_sizes, int n_in,
                              void* d_out, int out_size, void* d_ws, size_t ws_size,
                              hipStream_t stream)
{
    const float* x         = (const float*)d_in[0];
    const float* patch_w   = (const float*)d_in[1];
    const float* patch_b   = (const float*)d_in[2];
    const float* pos_embed = (const float*)d_in[3];
    const float* in_proj_w = (const float*)d_in[4];
    const float* conv_w    = (const float*)d_in[5];
    const float* conv_b    = (const float*)d_in[6];
    const float* xproj_w   = (const float*)d_in[7];
    const float* dtproj_w  = (const float*)d_in[8];
    const float* dtproj_b  = (const float*)d_in[9];
    const float* A_log     = (const float*)d_in[10];
    const float* D_param   = (const float*)d_in[11];
    const float* outproj_w = (const float*)d_in[12];
    const float* norm_w    = (const float*)d_in[13];
    const float* conv_wb   = (const float*)d_in[14];
    const float* conv_bb   = (const float*)d_in[15];
    const float* xproj_wb  = (const float*)d_in[16];
    const float* dtproj_wb = (const float*)d_in[17];
    const float* dtproj_bb = (const float*)d_in[18];
    const float* A_log_b   = (const float*)d_in[19];
    const float* D_b       = (const float*)d_in[20];
    const float* norm_f_w  = (const float*)d_in[21];

    // ---- carve (~56 MB; ws ~268 MB per fillBuffer WRITE_SIZE evidence)
    float* pf   = (float*)d_ws;
    float* h    = pf;  pf += (size_t)Mn*En;
    float* h2   = pf;  pf += (size_t)Mn*En;            // split-K partial (z=1)
    float* res  = pf;  pf += (size_t)Mn*En;
    float* xd   = pf;  pf += (size_t)2*Mn*40;          // [dir][m][40]
    float* Hsum = pf;  pf += (size_t)2*Bn*NC*Din*Sn;   // [dir][b][c][d][8]
    float* dtsm = pf;  pf += (size_t)2*Bn*NC*Din;
    unsigned short* ub = (unsigned short*)pf;
    unsigned short* xz = ub;  ub += (size_t)Mn*1536;
    unsigned short* u  = ub;  ub += (size_t)2*Mn*Din;   // [dir][m][d]; hn overlays
    unsigned short* hn = u;
    unsigned short* yt = ub;  ub += (size_t)2*Mn*Din;   // [dir][m][d]
    unsigned short* w_in = ub;  ub += (size_t)NW0;      // bf16 weights
    unsigned short* w_out= ub;  ub += (size_t)NW1;
    unsigned short* w_xf = ub;  ub += (size_t)NW2;
    unsigned short* w_xb = ub;  ub += (size_t)NW3;
    unsigned short* w_pm = ub;  ub += (size_t)NW4;
    unsigned short* pm = (unsigned short*)Hsum;         // overlay: pre-loop only
    size_t needed = (size_t)((char*)ub - (char*)d_ws);
    if (ws_size < needed) return;

    const int wave_blocks = (Mn*64)/256;             // 392
    const int B_me   = (Mn*En + 255)/256;
    const int B_md   = (Mn*768 + 255)/256;           // 4704
    const int B_cw   = ((NW0+NW1+NW2+NW3+NW4)/4 + 255)/256;
    const int mTiles = (Mn + 63)/64;                 // 25

    // ---- weight pre-cast + patch embed (patch GEMM split-K x2: h, h2)
    k_castw<<<B_cw, 256, 0, stream>>>(in_proj_w, outproj_w, xproj_w, xproj_wb,
                                      patch_w, w_in, w_out, w_xf, w_xb, w_pm);
    k_patch<<<B_md, 256, 0, stream>>>(x, pm);
    dim3 g0((En/64)*2, mTiles);
    gemm_mfma<float,0,2><<<g0, 256, 0, stream>>>(pm, nullptr, nullptr, w_pm,
                                                 h, En, Mn, En, 768, 1);
    k_posadd<<<B_me, 256, 0, stream>>>(h, h2, patch_b, pos_embed);

    for (int i = 0; i < DEPTH; ++i) {
        int ndir = (i < NSPA) ? 2 : 1;
        rms_residual<<<wave_blocks, 256, 0, stream>>>(h, h2, res, hn,
                                                      norm_w + (size_t)i*En, i == 0);

        dim3 g1(1536/64, mTiles);
        gemm_mfma<unsigned short,0,1><<<g1, 256, 0, stream>>>(
            hn, nullptr, nullptr, w_in + (size_t)i*1536*En,
            xz, 1536, Mn, 1536, En, 1);

        const float* cwf = conv_w + (size_t)i*Din*4;
        const float* cbf = conv_b + (size_t)i*Din;
        const float* dwf = dtproj_w + (size_t)i*Din*Rn;
        const float* dbf = dtproj_b + (size_t)i*Din;
        const float* Alf = A_log + (size_t)i*Din*Sn;
        const float* Dpf = D_param + (size_t)i*Din;
        const float* cwb = conv_wb + (size_t)i*Din*4;
        const float* cbb = conv_bb + (size_t)i*Din;
        const float* dwb = dtproj_wb + (size_t)i*Din*Rn;
        const float* dbb = dtproj_bb + (size_t)i*Din;
        const float* Alb = A_log_b + (size_t)i*Din*Sn;
        const float* Dpb = D_b + (size_t)i*Din;
        const unsigned short* xwf = w_xf + (size_t)i*40*Din;
        const unsigned short* xwb = w_xb + (size_t)i*40*Din;

        int c_blocks  = (ndir*Mn*Din + 255)/256;
        int sA_blocks = (ndir*Bn*NC*Din + 255)/256;
        int sB_blocks = (ndir*Bn*Din*Sn + 255)/256;

        k_conv2<<<c_blocks, 256, 0, stream>>>(xz, cwf, cbf, cwb, cbb, u, ndir);
        dim3 gx(ndir, mTiles);
        xproj_gemm<<<gx, 256, 0, stream>>>(u, xwf, xwb, xd);
        scanA<<<sA_blocks, 256, 0, stream>>>(u, xd, dwf, dbf, dwb, dbb,
                                             Alf, Alb, Hsum, dtsm, ndir);
        scanB<<<sB_blocks, 256, 0, stream>>>(Alf, Alb, Hsum, dtsm, ndir);
        scanC<<<sA_blocks, 256, 0, stream>>>(u, xd, dwf, dbf, dwb, dbb,
                                             Alf, Alb, Dpf, Dpb, Hsum, yt, ndir);

        dim3 g2((En/64)*2, mTiles);
        gemm_mfma<float,1,2><<<g2, 256, 0, stream>>>(
            yt, yt + (size_t)Mn*Din, xz + Din, w_out + (size_t)i*En*Din,
            h, En, Mn, En, Din, ndir);
    }

    final_k<<<wave_blocks, 256, 0, stream>>>(h, h2, res, norm_f_w, (float*)d_out);
}

// Round 12
// 1149.422 us; speedup vs baseline: 4.8748x; 1.0428x over previous
//
#include <hip/hip_runtime.h>
#include <hip/hip_bf16.h>
#include <math.h>

// EndoMamba r25: r24 + gate hoisted out of the out_proj GEMM.
// The GATED A-staging recomputed (yf+yb)*silu(z) (16 exp + 32 cvt per thread
// per K-step) 6x per element (once per n-tile/split-K block) on the K-loop
// critical path. k_gate now computes ag = f2us((yf+yb)*silu(z)) ONCE in a
// streaming elementwise kernel (bit-identical rounding point), and out_proj
// is a plain bf16 GEMM. Everything else identical to r24 (1198.6 us).
#define Bn   2
#define Tn   4
#define Nn   196
#define Ln   784
#define Mn   1568
#define En   384
#define Din  768
#define Sn   8
#define Rn   24
#define DEPTH 12
#define NSPA 6
#define NC   98
#define CL   8      // 784 = 98*8

typedef __attribute__((ext_vector_type(8))) short bf16x8;
typedef __attribute__((ext_vector_type(4))) float f32x4;

__device__ __forceinline__ float siluf(float v) { return v / (1.f + __expf(-v)); }
__device__ __forceinline__ float us2f(unsigned short u) {
    union { unsigned int i; float f; } v; v.i = (unsigned)u << 16; return v.f;
}
__device__ __forceinline__ unsigned short f2us(float f) {
    __hip_bfloat16 b = __float2bfloat16(f);
    return *(unsigned short*)&b;
}
__device__ __forceinline__ void cstore(float* p, float v) { *p = v; }
__device__ __forceinline__ void cstore(unsigned short* p, float v) { *p = f2us(v); }

// bijective XCD swizzle (m204): consecutive flats within an XCD share n-tile
__device__ __forceinline__ void xcd_tile(int ny, int& n0, int& m0)
{
    int nx = gridDim.x;
    int total = nx*ny;
    int bid = blockIdx.y*nx + blockIdx.x;
    int q = total >> 3, r = total & 7;
    int xcd = bid & 7, idx = bid >> 3;
    int base = (xcd < r) ? xcd*(q+1) : r*(q+1) + (xcd - r)*q;
    int flat = base + idx;
    n0 = (flat / ny) * 64;
    m0 = (flat % ny) * 64;
}

// -------------------- weight pre-cast fp32 -> bf16 (once per launch)
#define NW0 7077888   // in_proj 12*1536*384
#define NW1 3538944   // outproj 12*384*768
#define NW2 368640    // xproj fwd 12*40*768
#define NW3 184320    // xproj bwd 6*40*768
#define NW4 294912    // patch 384*768
__device__ __forceinline__ void cast4(unsigned short* d, const float* s)
{
    float4 v = *(const float4*)s;
    ushort4 o;
    o.x = f2us(v.x); o.y = f2us(v.y); o.z = f2us(v.z); o.w = f2us(v.w);
    *(ushort4*)d = o;
}
__global__ __launch_bounds__(256) void k_castw(
    const float* __restrict__ w0, const float* __restrict__ w1,
    const float* __restrict__ w2, const float* __restrict__ w3,
    const float* __restrict__ w4,
    unsigned short* __restrict__ o0, unsigned short* __restrict__ o1,
    unsigned short* __restrict__ o2, unsigned short* __restrict__ o3,
    unsigned short* __restrict__ o4)
{
    int i4 = (blockIdx.x*blockDim.x + threadIdx.x)*4;
    if (i4 < NW0) { cast4(o0+i4, w0+i4); return; }
    i4 -= NW0;
    if (i4 < NW1) { cast4(o1+i4, w1+i4); return; }
    i4 -= NW1;
    if (i4 < NW2) { cast4(o2+i4, w2+i4); return; }
    i4 -= NW2;
    if (i4 < NW3) { cast4(o3+i4, w3+i4); return; }
    i4 -= NW3;
    if (i4 < NW4) { cast4(o4+i4, w4+i4); }
}

// ------------------------------------------- patch gather -> pm[m,768] bf16
__global__ __launch_bounds__(256) void k_patch(
    const float* __restrict__ x, unsigned short* __restrict__ pm)
{
    int gid = blockIdx.x*blockDim.x + threadIdx.x;
    if (gid >= Mn*768) return;
    int idx = gid % 768, token = gid / 768;
    int b = token / Ln, l = token % Ln;
    int t = l / Nn, n = l % Nn;
    int hh = n / 14, ww = n % 14;
    int c = idx >> 8, rem = idx & 255, p = rem >> 4, q = rem & 15;
    pm[gid] = f2us(x[(((size_t)(b*3 + c)*Tn + t)*224 + (hh*16 + p))*224 + (ww*16 + q)]);
}

// ---------------- embed epilogue: h = h + h2 + pb + pos + pe (split-K add)
__global__ __launch_bounds__(256) void k_posadd(
    float* __restrict__ h, const float* __restrict__ h2,
    const float* __restrict__ pb, const float* __restrict__ pos)
{
    int gid = blockIdx.x*blockDim.x + threadIdx.x;
    if (gid >= Mn*En) return;
    int e = gid % En, token = gid / En;
    int l = token % Ln;
    int t = l / Nn, n = l % Nn;
    float div = __expf(-logf(10000.f) * (float)(e & ~1) / (float)En);
    float ang = (float)t * div;
    h[gid] += h2[gid] + pb[e] + pos[n*En + e] + ((e & 1) ? cosf(ang) : sinf(ang));
}

// -------------------- rmsnorm (+ residual); h2 = split-K partial of out_proj
__global__ __launch_bounds__(256) void rms_residual(
    const float* __restrict__ hin, const float* __restrict__ h2,
    float* __restrict__ res, unsigned short* __restrict__ hn,
    const float* __restrict__ w, int first)
{
    int wid  = (blockIdx.x * blockDim.x + threadIdx.x) >> 6;   // token
    int lane = threadIdx.x & 63;
    if (wid >= Mn) return;
    const float* hp = hin + (size_t)wid*En;
    const float* h2p = h2 + (size_t)wid*En;
    float* rp = res + (size_t)wid*En;
    float v[6]; float ss = 0.f;
    #pragma unroll
    for (int j = 0; j < 6; ++j) {
        int e = lane + j*64;
        float r = first ? hp[e] : (hp[e] + h2p[e] + rp[e]);
        v[j] = r; ss = fmaf(r, r, ss);
    }
    #pragma unroll
    for (int off = 32; off; off >>= 1) ss += __shfl_xor(ss, off, 64);
    float scale = rsqrtf(ss * (1.f/(float)En) + 1e-5f);
    #pragma unroll
    for (int j = 0; j < 6; ++j) {
        int e = lane + j*64;
        rp[e] = v[j];
        hn[(size_t)wid*En + e] = f2us(v[j] * scale * w[e]);
    }
}

// ---------------- bf16 MFMA GEMM: C = A[M,K] * Wb[N,K]^T, Wb bf16 (pre-cast)
// BK=64 double-buffered, one barrier per step, XCD-swizzled tiles.
// SK: split-K factor; z-th partial written to C + z*M*ldc.
template<typename CT, int SK>
__global__ __launch_bounds__(256) void gemm_mfma(
    const unsigned short* __restrict__ A,     // bf16 A [M][K]
    const unsigned short* __restrict__ Wb,    // bf16 W [N][K]
    CT* __restrict__ C, int ldc, int M, int N, int K)
{
    __shared__ unsigned short As[2][64][72];   // 64 k + 8 pad
    __shared__ unsigned short Bs[2][64][72];
    int n0, m0;
    xcd_tile((M + 63) >> 6, n0, m0);
    int nidx = n0 >> 6;
    int zk = nidx % SK;
    n0 = (nidx / SK) * 64;
    int kbeg = zk * (K / SK);
    int kend = kbeg + K / SK;
    CT* Cz = C + (size_t)zk*M*ldc;
    int tid = threadIdx.x;
    int wave = tid >> 6, lane = tid & 63;
    int quad = lane >> 4, fr = lane & 15;
    int arow = tid >> 2;            // 0..63
    int c8   = (tid & 3) << 3;      // 0,8,16,24
    int mg = m0 + arow; if (mg >= M) mg = M - 1;
    f32x4 acc[4] = {};

    auto load_tile = [&](int k0, bf16x8& av0, bf16x8& av1,
                         bf16x8& wv0, bf16x8& wv1) {
        av0 = *(const bf16x8*)(A + (size_t)mg*K + k0 + c8);
        av1 = *(const bf16x8*)(A + (size_t)mg*K + k0 + c8 + 32);
        wv0 = *(const bf16x8*)(Wb + (size_t)(n0 + arow)*K + k0 + c8);
        wv1 = *(const bf16x8*)(Wb + (size_t)(n0 + arow)*K + k0 + c8 + 32);
    };

    {   // prologue: stage first k-tile into buffer 0
        bf16x8 a0, a1, w0, w1;
        load_tile(kbeg, a0, a1, w0, w1);
        *(bf16x8*)&As[0][arow][c8]      = a0;
        *(bf16x8*)&As[0][arow][c8 + 32] = a1;
        *(bf16x8*)&Bs[0][arow][c8]      = w0;
        *(bf16x8*)&Bs[0][arow][c8 + 32] = w1;
    }
    int cur = 0;
    for (int k0 = kbeg + 64; k0 <= kend; k0 += 64) {
        bool more = (k0 < kend);
        bf16x8 a0, a1, w0, w1;
        if (more) load_tile(k0, a0, a1, w0, w1);   // issue loads before barrier
        __syncthreads();
        bf16x8 af0 = *(const bf16x8*)&As[cur][wave*16 + fr][quad << 3];
        bf16x8 af1 = *(const bf16x8*)&As[cur][wave*16 + fr][(quad << 3) + 32];
        #pragma unroll
        for (int nt = 0; nt < 4; ++nt) {
            bf16x8 b0 = *(const bf16x8*)&Bs[cur][nt*16 + fr][quad << 3];
            bf16x8 b1 = *(const bf16x8*)&Bs[cur][nt*16 + fr][(quad << 3) + 32];
            acc[nt] = __builtin_amdgcn_mfma_f32_16x16x32_bf16(af0, b0, acc[nt], 0, 0, 0);
            acc[nt] = __builtin_amdgcn_mfma_f32_16x16x32_bf16(af1, b1, acc[nt], 0, 0, 0);
        }
        if (more) {
            *(bf16x8*)&As[cur^1][arow][c8]      = a0;
            *(bf16x8*)&As[cur^1][arow][c8 + 32] = a1;
            *(bf16x8*)&Bs[cur^1][arow][c8]      = w0;
            *(bf16x8*)&Bs[cur^1][arow][c8 + 32] = w1;
            cur ^= 1;
        }
    }
    #pragma unroll
    for (int nt = 0; nt < 4; ++nt) {
        #pragma unroll
        for (int r = 0; r < 4; ++r) {
            int mgo = m0 + wave*16 + quad*4 + r;
            if (mgo < M) cstore(Cz + (size_t)mgo*ldc + n0 + nt*16 + fr, acc[nt][r]);
        }
    }
}

// ------ u = silu(conv(xz)) both dirs in one launch: u[dir][m][d] bf16
// (streaming, full-grid parallelism — 9408 blocks; do NOT fuse into xproj)
__global__ __launch_bounds__(256) void k_conv2(
    const unsigned short* __restrict__ xz,
    const float* __restrict__ cwf, const float* __restrict__ cbf,
    const float* __restrict__ cwb, const float* __restrict__ cbb,
    unsigned short* __restrict__ u, int ndir)
{
    int gid = blockIdx.x*blockDim.x + threadIdx.x;
    if (gid >= ndir*Mn*Din) return;
    int dir = gid / (Mn*Din);
    int rem = gid % (Mn*Din);
    int d = rem % Din, m = rem / Din;
    int l = m % Ln, b = m / Ln;
    const float* cw = dir ? cwb : cwf;
    const float* cb = dir ? cbb : cbf;
    float4 cwv = *(const float4*)(cw + d*4);
    float acc = cb[d];
    #pragma unroll
    for (int k = 0; k < 4; ++k) {
        int ls = l - 3 + k;
        if (ls < 0) continue;
        int lsrc = dir ? (Ln - 1 - ls) : ls;
        float cwk = (k==0)?cwv.x:(k==1)?cwv.y:(k==2)?cwv.z:cwv.w;
        acc = fmaf(us2f(xz[(size_t)(b*Ln + lsrc)*1536 + d]), cwk, acc);
    }
    u[gid] = f2us(siluf(acc));
}

// ------ gate: ag[m][k] = f2us((yf + (ndir==2? yb:0)) * silu(z)) ONCE
// (was recomputed 6x inside the out_proj GEMM's A-staging; bit-identical
// rounding point — same value that previously fed the MFMA)
__global__ __launch_bounds__(256) void k_gate(
    const unsigned short* __restrict__ yf, const unsigned short* __restrict__ yb,
    const unsigned short* __restrict__ z,   // row stride 1536
    unsigned short* __restrict__ ag, int ndir)
{
    int gid = blockIdx.x*blockDim.x + threadIdx.x;
    if (gid >= Mn*Din) return;
    int m = gid / Din, k = gid % Din;
    float v = us2f(yf[gid]);
    if (ndir == 2) v += us2f(yb[gid]);
    ag[gid] = f2us(v * siluf(us2f(z[(size_t)m*1536 + k])));
}

// ------ xproj as MFMA GEMM: xd[dir][m][40] = u[dir][m][768] * xw[40][768]^T
// BK=64, one 64-wide N-tile (W rows 40..63 clamped, cols >=40 not stored).
// grid = (ndir, 25), swizzled; W bf16 pre-cast, selected per dir.
__global__ __launch_bounds__(256) void xproj_gemm(
    const unsigned short* __restrict__ u,
    const unsigned short* __restrict__ xwf, const unsigned short* __restrict__ xwb,
    float* __restrict__ xd)
{
    __shared__ unsigned short As[2][64][72];
    __shared__ unsigned short Bs[2][64][72];
    int n0d, m0;
    xcd_tile((Mn + 63) >> 6, n0d, m0);
    int dir = n0d >> 6;                       // n-tile index == dir
    const unsigned short* A = u + (size_t)dir*Mn*Din;
    const unsigned short* W = dir ? xwb : xwf;
    float* C = xd + (size_t)dir*Mn*40;
    int tid = threadIdx.x;
    int wave = tid >> 6, lane = tid & 63;
    int quad = lane >> 4, fr = lane & 15;
    int arow = tid >> 2;
    int c8   = (tid & 3) << 3;
    int mg = m0 + arow; if (mg >= Mn) mg = Mn - 1;
    int wrow = arow < 40 ? arow : 39;
    f32x4 acc[4] = {};

    auto load_tile = [&](int k0, bf16x8& av0, bf16x8& av1,
                         bf16x8& wv0, bf16x8& wv1) {
        av0 = *(const bf16x8*)(A + (size_t)mg*Din + k0 + c8);
        av1 = *(const bf16x8*)(A + (size_t)mg*Din + k0 + c8 + 32);
        wv0 = *(const bf16x8*)(W + (size_t)wrow*Din + k0 + c8);
        wv1 = *(const bf16x8*)(W + (size_t)wrow*Din + k0 + c8 + 32);
    };

    {
        bf16x8 a0, a1, w0, w1;
        load_tile(0, a0, a1, w0, w1);
        *(bf16x8*)&As[0][arow][c8]      = a0;
        *(bf16x8*)&As[0][arow][c8 + 32] = a1;
        *(bf16x8*)&Bs[0][arow][c8]      = w0;
        *(bf16x8*)&Bs[0][arow][c8 + 32] = w1;
    }
    int cur = 0;
    for (int k0 = 64; k0 <= Din; k0 += 64) {
        bool more = (k0 < Din);
        bf16x8 a0, a1, w0, w1;
        if (more) load_tile(k0, a0, a1, w0, w1);
        __syncthreads();
        bf16x8 af0 = *(const bf16x8*)&As[cur][wave*16 + fr][quad << 3];
        bf16x8 af1 = *(const bf16x8*)&As[cur][wave*16 + fr][(quad << 3) + 32];
        #pragma unroll
        for (int nt = 0; nt < 4; ++nt) {
            bf16x8 b0 = *(const bf16x8*)&Bs[cur][nt*16 + fr][quad << 3];
            bf16x8 b1 = *(const bf16x8*)&Bs[cur][nt*16 + fr][(quad << 3) + 32];
            acc[nt] = __builtin_amdgcn_mfma_f32_16x16x32_bf16(af0, b0, acc[nt], 0, 0, 0);
            acc[nt] = __builtin_amdgcn_mfma_f32_16x16x32_bf16(af1, b1, acc[nt], 0, 0, 0);
        }
        if (more) {
            *(bf16x8*)&As[cur^1][arow][c8]      = a0;
            *(bf16x8*)&As[cur^1][arow][c8 + 32] = a1;
            *(bf16x8*)&Bs[cur^1][arow][c8]      = w0;
            *(bf16x8*)&Bs[cur^1][arow][c8 + 32] = w1;
            cur ^= 1;
        }
    }
    #pragma unroll
    for (int nt = 0; nt < 4; ++nt) {
        int col = nt*16 + fr;
        if (col >= 40) continue;
        #pragma unroll
        for (int r = 0; r < 4; ++r) {
            int mgo = m0 + wave*16 + quad*4 + r;
            if (mgo < Mn) C[(size_t)mgo*40 + col] = acc[nt][r];
        }
    }
}

// ---------------- scan phase A: per-chunk (Sdt, H[8]); dt inline; both dirs
__global__ __launch_bounds__(256) void scanA(
    const unsigned short* __restrict__ u, const float* __restrict__ xd,
    const float* __restrict__ dwf, const float* __restrict__ dbf,
    const float* __restrict__ dwb, const float* __restrict__ dbb,
    const float* __restrict__ Alf, const float* __restrict__ Alb,
    float* __restrict__ Hsum, float* __restrict__ dtsum, int ndir)
{
    int gid = blockIdx.x*blockDim.x + threadIdx.x;
    if (gid >= ndir*Bn*NC*Din) return;
    int dir = gid / (Bn*NC*Din);
    int rem = gid % (Bn*NC*Din);
    int d = rem % Din;
    int bc = rem / Din;
    int c = bc % NC, b = bc / NC;
    const float* A_log = dir ? Alb : Alf;
    const float* dw = dir ? dwb : dwf;
    const float* db = dir ? dbb : dbf;
    float A[Sn];
    #pragma unroll
    for (int s = 0; s < Sn; ++s) A[s] = -__expf(A_log[d*Sn + s]);
    float dwr[Rn];
    #pragma unroll
    for (int r = 0; r < Rn; ++r) dwr[r] = dw[d*Rn + r];
    float dbv = db[d];
    float hs[Sn] = {0,0,0,0,0,0,0,0};
    float sdt = 0.f;
    int l0 = c*CL;
    const unsigned short* up = u + (size_t)dir*Mn*Din + ((size_t)b*Ln + l0)*Din + d;
    const float* xp = xd + (size_t)dir*Mn*40 + ((size_t)b*Ln + l0)*40;
    #pragma unroll
    for (int l = 0; l < CL; ++l) {
        float uv = us2f(up[(size_t)l*Din]);
        const float* xr = xp + l*40;
        float dta = dbv;
        #pragma unroll
        for (int r = 0; r < Rn; ++r) dta = fmaf(xr[r], dwr[r], dta);
        float dtv = (dta > 20.f) ? dta : log1pf(__expf(dta));
        sdt += dtv;
        const float4* B4 = (const float4*)(xr + Rn);
        float4 Bv0 = B4[0], Bv1 = B4[1];
        float du = dtv * uv;
        hs[0] = fmaf(__expf(dtv*A[0]), hs[0], du*Bv0.x);
        hs[1] = fmaf(__expf(dtv*A[1]), hs[1], du*Bv0.y);
        hs[2] = fmaf(__expf(dtv*A[2]), hs[2], du*Bv0.z);
        hs[3] = fmaf(__expf(dtv*A[3]), hs[3], du*Bv0.w);
        hs[4] = fmaf(__expf(dtv*A[4]), hs[4], du*Bv1.x);
        hs[5] = fmaf(__expf(dtv*A[5]), hs[5], du*Bv1.y);
        hs[6] = fmaf(__expf(dtv*A[6]), hs[6], du*Bv1.z);
        hs[7] = fmaf(__expf(dtv*A[7]), hs[7], du*Bv1.w);
    }
    float4* Hp = (float4*)(Hsum + (size_t)gid*8);
    Hp[0] = make_float4(hs[0], hs[1], hs[2], hs[3]);
    Hp[1] = make_float4(hs[4], hs[5], hs[6], hs[7]);
    dtsum[gid] = sdt;
}

// ---------------- scan phase B: serial fixup IN-PLACE on Hsum, both dirs.
__global__ __launch_bounds__(256) void scanB(
    const float* __restrict__ Alf, const float* __restrict__ Alb,
    float* __restrict__ Hsum, const float* __restrict__ dtsum, int ndir)
{
    int gid = blockIdx.x*blockDim.x + threadIdx.x;
    if (gid >= ndir*Bn*Din*Sn) return;
    int s   = gid & 7;
    int rem = gid >> 3;               // (dir*Bn + b)*Din + d
    int d   = rem % Din;
    int t   = rem / Din;
    int b   = t % Bn, dir = t / Bn;
    const float* A_log = dir ? Alb : Alf;
    float Av = -__expf(A_log[d*Sn + s]);
    float h = 0.f;
    size_t base = (size_t)dir*Bn*NC*Din + (size_t)b*NC*Din + d;
    float* Hp = Hsum + base*8 + s;
    const float* dp = dtsum + base;
    #pragma unroll 7
    for (int c = 0; c < NC; ++c) {
        size_t off = (size_t)c*Din;
        float H = Hp[off*8];
        float sdt = dp[off];
        Hp[off*8] = h;
        h = fmaf(__expf(Av*sdt), h, H);
    }
}

// -------- scan phase C: seeded local scan, raw y emit (no gate), both dirs
__global__ __launch_bounds__(256) void scanC(
    const unsigned short* __restrict__ u, const float* __restrict__ xd,
    const float* __restrict__ dwf, const float* __restrict__ dbf,
    const float* __restrict__ dwb, const float* __restrict__ dbb,
    const float* __restrict__ Alf, const float* __restrict__ Alb,
    const float* __restrict__ Dpf, const float* __restrict__ Dpb,
    const float* __restrict__ Hsum, unsigned short* __restrict__ yt, int ndir)
{
    int gid = blockIdx.x*blockDim.x + threadIdx.x;
    if (gid >= ndir*Bn*NC*Din) return;
    int dir = gid / (Bn*NC*Din);
    int rem = gid % (Bn*NC*Din);
    int d = rem % Din;
    int bc = rem / Din;
    int c = bc % NC, b = bc / NC;
    const float* A_log = dir ? Alb : Alf;
    const float* dw = dir ? dwb : dwf;
    const float* db = dir ? dbb : dbf;
    const float* Dp = dir ? Dpb : Dpf;
    float A[Sn];
    #pragma unroll
    for (int s = 0; s < Sn; ++s) A[s] = -__expf(A_log[d*Sn + s]);
    float dwr[Rn];
    #pragma unroll
    for (int r = 0; r < Rn; ++r) dwr[r] = dw[d*Rn + r];
    float dbv = db[d];
    const float4* hp = (const float4*)(Hsum + (size_t)gid*8);
    float4 h0 = hp[0], h1 = hp[1];
    float hs[Sn] = {h0.x, h0.y, h0.z, h0.w, h1.x, h1.y, h1.z, h1.w};
    float Dd = Dp[d];
    int l0 = c*CL;
    const unsigned short* up = u + (size_t)dir*Mn*Din + ((size_t)b*Ln + l0)*Din + d;
    const float* xp = xd + (size_t)dir*Mn*40 + ((size_t)b*Ln + l0)*40;
    unsigned short* yp = yt + (size_t)dir*Mn*Din + (size_t)b*Ln*Din + d;
    #pragma unroll
    for (int l = 0; l < CL; ++l) {
        int gl = l0 + l;
        float uv = us2f(up[(size_t)l*Din]);
        const float* xr = xp + l*40;
        float dta = dbv;
        #pragma unroll
        for (int r = 0; r < Rn; ++r) dta = fmaf(xr[r], dwr[r], dta);
        float dtv = (dta > 20.f) ? dta : log1pf(__expf(dta));
        const float4* B4 = (const float4*)(xr + Rn);
        float4 Bv0 = B4[0], Bv1 = B4[1], Cv0 = B4[2], Cv1 = B4[3];
        float du = dtv * uv;
        float yv = 0.f;
        hs[0] = fmaf(__expf(dtv*A[0]), hs[0], du*Bv0.x); yv = fmaf(hs[0], Cv0.x, yv);
        hs[1] = fmaf(__expf(dtv*A[1]), hs[1], du*Bv0.y); yv = fmaf(hs[1], Cv0.y, yv);
        hs[2] = fmaf(__expf(dtv*A[2]), hs[2], du*Bv0.z); yv = fmaf(hs[2], Cv0.z, yv);
        hs[3] = fmaf(__expf(dtv*A[3]), hs[3], du*Bv0.w); yv = fmaf(hs[3], Cv0.w, yv);
        hs[4] = fmaf(__expf(dtv*A[4]), hs[4], du*Bv1.x); yv = fmaf(hs[4], Cv1.x, yv);
        hs[5] = fmaf(__expf(dtv*A[5]), hs[5], du*Bv1.y); yv = fmaf(hs[5], Cv1.y, yv);
        hs[6] = fmaf(__expf(dtv*A[6]), hs[6], du*Bv1.z); yv = fmaf(hs[6], Cv1.z, yv);
        hs[7] = fmaf(__expf(dtv*A[7]), hs[7], du*Bv1.w); yv = fmaf(hs[7], Cv1.w, yv);
        yv = fmaf(uv, Dd, yv);
        int ol = dir ? (Ln - 1 - gl) : gl;
        yp[(size_t)ol*Din] = f2us(yv);
    }
}

// ------------------------- final rmsnorm (h + h2 + res), h2 = split-K partial
__global__ __launch_bounds__(256) void final_k(
    const float* __restrict__ h, const float* __restrict__ h2,
    const float* __restrict__ res, const float* __restrict__ w,
    float* __restrict__ out)
{
    int wid  = (blockIdx.x * blockDim.x + threadIdx.x) >> 6;
    int lane = threadIdx.x & 63;
    if (wid >= Mn) return;
    const float* hp = h + (size_t)wid*En;
    const float* h2p = h2 + (size_t)wid*En;
    const float* rp = res + (size_t)wid*En;
    float v[6]; float ss = 0.f;
    #pragma unroll
    for (int j = 0; j < 6; ++j) {
        int e = lane + j*64;
        float r = hp[e] + h2p[e] + rp[e];
        v[j] = r; ss = fmaf(r, r, ss);
    }
    #pragma unroll
    for (int off = 32; off; off >>= 1) ss += __shfl_xor(ss, off, 64);
    float scale = rsqrtf(ss * (1.f/(float)En) + 1e-5f);
    #pragma unroll
    for (int j = 0; j < 6; ++j) {
        int e = lane + j*64;
        out[(size_t)wid*En + e] = v[j] * scale * w[e];
    }
}

extern "C" void kernel_launch(void* const* d_in, const int* in_sizes, int n_in,
                              void* d_out, int out_size, void* d_ws, size_t ws_size,
                              hipStream_t stream)
{
    const float* x         = (const float*)d_in[0];
    const float* patch_w   = (const float*)d_in[1];
    const float* patch_b   = (const float*)d_in[2];
    const float* pos_embed = (const float*)d_in[3];
    const float* in_proj_w = (const float*)d_in[4];
    const float* conv_w    = (const float*)d_in[5];
    const float* conv_b    = (const float*)d_in[6];
    const float* xproj_w   = (const float*)d_in[7];
    const float* dtproj_w  = (const float*)d_in[8];
    const float* dtproj_b  = (const float*)d_in[9];
    const float* A_log     = (const float*)d_in[10];
    const float* D_param   = (const float*)d_in[11];
    const float* outproj_w = (const float*)d_in[12];
    const float* norm_w    = (const float*)d_in[13];
    const float* conv_wb   = (const float*)d_in[14];
    const float* conv_bb   = (const float*)d_in[15];
    const float* xproj_wb  = (const float*)d_in[16];
    const float* dtproj_wb = (const float*)d_in[17];
    const float* dtproj_bb = (const float*)d_in[18];
    const float* A_log_b   = (const float*)d_in[19];
    const float* D_b       = (const float*)d_in[20];
    const float* norm_f_w  = (const float*)d_in[21];

    // ---- carve (~58 MB; ws ~268 MB per fillBuffer WRITE_SIZE evidence)
    float* pf   = (float*)d_ws;
    float* h    = pf;  pf += (size_t)Mn*En;
    float* h2   = pf;  pf += (size_t)Mn*En;            // split-K partial (z=1)
    float* res  = pf;  pf += (size_t)Mn*En;
    float* xd   = pf;  pf += (size_t)2*Mn*40;          // [dir][m][40]
    float* Hsum = pf;  pf += (size_t)2*Bn*NC*Din*Sn;   // [dir][b][c][d][8]
    float* dtsm = pf;  pf += (size_t)2*Bn*NC*Din;
    unsigned short* ub = (unsigned short*)pf;
    unsigned short* xz = ub;  ub += (size_t)Mn*1536;
    unsigned short* u  = ub;  ub += (size_t)2*Mn*Din;   // [dir][m][d]; hn overlays
    unsigned short* hn = u;
    unsigned short* yt = ub;  ub += (size_t)2*Mn*Din;   // [dir][m][d]
    unsigned short* ag = ub;  ub += (size_t)Mn*Din;     // gated A for out_proj
    unsigned short* w_in = ub;  ub += (size_t)NW0;      // bf16 weights
    unsigned short* w_out= ub;  ub += (size_t)NW1;
    unsigned short* w_xf = ub;  ub += (size_t)NW2;
    unsigned short* w_xb = ub;  ub += (size_t)NW3;
    unsigned short* w_pm = ub;  ub += (size_t)NW4;
    unsigned short* pm = (unsigned short*)Hsum;         // overlay: pre-loop only
    size_t needed = (size_t)((char*)ub - (char*)d_ws);
    if (ws_size < needed) return;

    const int wave_blocks = (Mn*64)/256;             // 392
    const int B_me   = (Mn*En + 255)/256;
    const int B_md   = (Mn*768 + 255)/256;           // 4704
    const int B_cw   = ((NW0+NW1+NW2+NW3+NW4)/4 + 255)/256;
    const int mTiles = (Mn + 63)/64;                 // 25

    // ---- weight pre-cast + patch embed (patch GEMM split-K x2: h, h2)
    k_castw<<<B_cw, 256, 0, stream>>>(in_proj_w, outproj_w, xproj_w, xproj_wb,
                                      patch_w, w_in, w_out, w_xf, w_xb, w_pm);
    k_patch<<<B_md, 256, 0, stream>>>(x, pm);
    dim3 g0((En/64)*2, mTiles);
    gemm_mfma<float,2><<<g0, 256, 0, stream>>>(pm, w_pm, h, En, Mn, En, 768);
    k_posadd<<<B_me, 256, 0, stream>>>(h, h2, patch_b, pos_embed);

    for (int i = 0; i < DEPTH; ++i) {
        int ndir = (i < NSPA) ? 2 : 1;
        rms_residual<<<wave_blocks, 256, 0, stream>>>(h, h2, res, hn,
                                                      norm_w + (size_t)i*En, i == 0);

        dim3 g1(1536/64, mTiles);
        gemm_mfma<unsigned short,1><<<g1, 256, 0, stream>>>(
            hn, w_in + (size_t)i*1536*En, xz, 1536, Mn, 1536, En);

        const float* cwf = conv_w + (size_t)i*Din*4;
        const float* cbf = conv_b + (size_t)i*Din;
        const float* dwf = dtproj_w + (size_t)i*Din*Rn;
        const float* dbf = dtproj_b + (size_t)i*Din;
        const float* Alf = A_log + (size_t)i*Din*Sn;
        const float* Dpf = D_param + (size_t)i*Din;
        const float* cwb = conv_wb + (size_t)i*Din*4;
        const float* cbb = conv_bb + (size_t)i*Din;
        const float* dwb = dtproj_wb + (size_t)i*Din*Rn;
        const float* dbb = dtproj_bb + (size_t)i*Din;
        const float* Alb = A_log_b + (size_t)i*Din*Sn;
        const float* Dpb = D_b + (size_t)i*Din;
        const unsigned short* xwf = w_xf + (size_t)i*40*Din;
        const unsigned short* xwb = w_xb + (size_t)i*40*Din;

        int c_blocks  = (ndir*Mn*Din + 255)/256;
        int g_blocks  = (Mn*Din + 255)/256;
        int sA_blocks = (ndir*Bn*NC*Din + 255)/256;
        int sB_blocks = (ndir*Bn*Din*Sn + 255)/256;

        k_conv2<<<c_blocks, 256, 0, stream>>>(xz, cwf, cbf, cwb, cbb, u, ndir);
        dim3 gx(ndir, mTiles);
        xproj_gemm<<<gx, 256, 0, stream>>>(u, xwf, xwb, xd);
        scanA<<<sA_blocks, 256, 0, stream>>>(u, xd, dwf, dbf, dwb, dbb,
                                             Alf, Alb, Hsum, dtsm, ndir);
        scanB<<<sB_blocks, 256, 0, stream>>>(Alf, Alb, Hsum, dtsm, ndir);
        scanC<<<sA_blocks, 256, 0, stream>>>(u, xd, dwf, dbf, dwb, dbb,
                                             Alf, Alb, Dpf, Dpb, Hsum, yt, ndir);

        k_gate<<<g_blocks, 256, 0, stream>>>(yt, yt + (size_t)Mn*Din,
                                             xz + Din, ag, ndir);
        dim3 g2((En/64)*2, mTiles);
        gemm_mfma<float,2><<<g2, 256, 0, stream>>>(
            ag, w_out + (size_t)i*En*Din, h, En, Mn, En, Din);
    }

    final_k<<<wave_blocks, 256, 0, stream>>>(h, h2, res, norm_f_w, (float*)d_out);
}